// Round 21
// baseline (268.426 us; speedup 1.0000x reference)
//
#include <hip/hip_runtime.h>
#include <hip/hip_bf16.h>
#include <math.h>

#define B_ 2
#define T_ 2048
#define H_ 6
#define DK_ 256
#define DV_ 256
#define HID_ 2048
#define C_ 64
#define NC_ 32

typedef __attribute__((ext_vector_type(8))) short short8;
typedef __attribute__((ext_vector_type(4))) float f32x4;

__device__ __forceinline__ unsigned rnebf(float f) {
  unsigned u = __float_as_uint(f);
  return (u + 0x7fffu + ((u >> 16) & 1u)) >> 16;
}
__device__ __forceinline__ unsigned pkbf(float lo, float hi) {
  return rnebf(lo) | (rnebf(hi) << 16);
}
__device__ __forceinline__ float bf2f(unsigned u16v) {
  return __uint_as_float((u16v & 0xffffu) << 16);
}
__device__ __forceinline__ short8 u4_to_s8(uint4 u) {
  union { uint4 u; short8 s; } c; c.u = u; return c.s;
}

// async global->LDS 16B per lane; LDS dest wave-uniform base + lane*16
__device__ __forceinline__ void gload_lds16(const void* g, void* l) {
  __builtin_amdgcn_global_load_lds(
      (const __attribute__((address_space(1))) unsigned int*)g,
      (__attribute__((address_space(3))) unsigned int*)l, 16, 0, 0);
}

// Build MFMA B-fragment (16x16x32 bf16) for a k-tile from two C/D-layout
// packed mtiles Pe (even 16 rows) and Po (odd 16 rows).
__device__ __forceinline__ short8 buildB(uint2 Pe, uint2 Po, int lg, int c16) {
  const int src0 = ((2 * (lg & 1)) << 4) | c16;
  const int src1 = src0 + 16;
  int e0 = __shfl((int)Pe.x, src0), o0 = __shfl((int)Po.x, src0);
  int e1 = __shfl((int)Pe.y, src0), o1 = __shfl((int)Po.y, src0);
  int e2 = __shfl((int)Pe.x, src1), o2 = __shfl((int)Po.x, src1);
  int e3 = __shfl((int)Pe.y, src1), o3 = __shfl((int)Po.y, src1);
  const bool lo2 = (lg < 2);
  union { int i[4]; short8 s; } u;
  u.i[0] = lo2 ? e0 : o0;
  u.i[1] = lo2 ? e1 : o1;
  u.i[2] = lo2 ? e2 : o2;
  u.i[3] = lo2 ? e3 : o3;
  return u.s;
}

// ---------------------------------------------------------------------------
// Kernel 1: fused projections only
// ---------------------------------------------------------------------------
__global__ __launch_bounds__(256) void gdn_proj_kernel(
    const float* __restrict__ hab, const float* __restrict__ hg,
    const float* __restrict__ b_w, const float* __restrict__ a_w,
    const float* __restrict__ g_w, const float* __restrict__ A_log,
    const float* __restrict__ dt_bias,
    float* __restrict__ beta_o, float* __restrict__ g_o,
    float* __restrict__ sgate_o) {
  const int bt = blockIdx.x;
  const int tid = threadIdx.x;
  const int lane = tid & 63;
  const int wid = tid >> 6;

  const float* h1 = hab + (size_t)bt * HID_ + tid * 8;
  const float* h2 = hg + (size_t)bt * HID_ + tid * 8;
  const float4 xa = *(const float4*)(h1);
  const float4 xb = *(const float4*)(h1 + 4);
  const float4 ya = *(const float4*)(h2);
  const float4 yb = *(const float4*)(h2 + 4);

  float part[18];
#pragma unroll
  for (int n = 0; n < 6; ++n) {
    const float* wp = b_w + n * HID_ + tid * 8;
    const float4 w0 = *(const float4*)(wp);
    const float4 w1 = *(const float4*)(wp + 4);
    part[n] = xa.x * w0.x + xa.y * w0.y + xa.z * w0.z + xa.w * w0.w +
              xb.x * w1.x + xb.y * w1.y + xb.z * w1.z + xb.w * w1.w;
  }
#pragma unroll
  for (int n = 0; n < 6; ++n) {
    const float* wp = a_w + n * HID_ + tid * 8;
    const float4 w0 = *(const float4*)(wp);
    const float4 w1 = *(const float4*)(wp + 4);
    part[6 + n] = xa.x * w0.x + xa.y * w0.y + xa.z * w0.z + xa.w * w0.w +
                  xb.x * w1.x + xb.y * w1.y + xb.z * w1.z + xb.w * w1.w;
  }
#pragma unroll
  for (int n = 0; n < 6; ++n) {
    const float* wp = g_w + n * HID_ + tid * 8;
    const float4 w0 = *(const float4*)(wp);
    const float4 w1 = *(const float4*)(wp + 4);
    part[12 + n] = ya.x * w0.x + ya.y * w0.y + ya.z * w0.z + ya.w * w0.w +
                   yb.x * w1.x + yb.y * w1.y + yb.z * w1.z + yb.w * w1.w;
  }

  __shared__ float red[18][4];
#pragma unroll
  for (int i = 0; i < 18; ++i) {
    float x = part[i];
    x += __shfl_xor(x, 1);
    x += __shfl_xor(x, 2);
    x += __shfl_xor(x, 4);
    x += __shfl_xor(x, 8);
    x += __shfl_xor(x, 16);
    x += __shfl_xor(x, 32);
    if (lane == 0) red[i][wid] = x;
  }
  __syncthreads();

  if (tid < 18) {
    const float s = red[tid][0] + red[tid][1] + red[tid][2] + red[tid][3];
    if (tid < 6) {
      beta_o[(size_t)bt * H_ + tid] = 1.f / (1.f + __expf(-s));
    } else if (tid < 12) {
      const int n = tid - 6;
      const float x = s + dt_bias[n];
      const float sp = (x > 20.f) ? x : log1pf(__expf(x));
      g_o[(size_t)bt * H_ + n] = -__expf(A_log[n]) * sp;
    } else {
      const int n = tid - 12;
      sgate_o[(size_t)bt * H_ + n] = s / (1.f + __expf(-s));
    }
  }
}

// ---------------------------------------------------------------------------
// Kernel 2: per-chunk inclusive cumsum of g; lam = exp(gend)
// ---------------------------------------------------------------------------
__global__ __launch_bounds__(256) void gdn_cum_kernel(
    const float* __restrict__ g, float* __restrict__ Gc,
    float* __restrict__ lam) {
  const int bh = blockIdx.x;
  const int b = bh / H_, h = bh - b * H_;
  const int w = threadIdx.x >> 6, l = threadIdx.x & 63;
  for (int it = 0; it < 8; ++it) {
    const int nc = it * 4 + w;
    const int tg = nc * C_ + l;
    const size_t srow = ((size_t)b * T_ + tg) * H_ + h;
    float val = g[srow];
#pragma unroll
    for (int ofs = 1; ofs < 64; ofs <<= 1) {
      const float o = __shfl_up(val, ofs);
      if (l >= ofs) val += o;
    }
    Gc[(bh * NC_ + nc) * C_ + l] = val;
    if (l == 63) lam[bh * NC_ + nc] = __expf(val);
  }
}

// ---------------------------------------------------------------------------
// Kernel 3a (parallel, LDS-heavy phase): stages RAW q/k bf16; M=q.k^T,
// A=k.k^T, diag -> sq/sk via MFMA; emits Qd, kT, M, PRE-FS W (kn*bWl, bf16)
// and AlT -> GLOBAL (fp32). LDS 75.3 KB -> 2 blocks/CU. (R20-proven)
// ---------------------------------------------------------------------------
__global__ __launch_bounds__(256) void gdn_prep_mfma_kernel(
    const float* __restrict__ q, const float* __restrict__ k,
    const float* __restrict__ beta, const float* __restrict__ Gc,
    ushort* __restrict__ wWp, ushort* __restrict__ wMp,
    ushort* __restrict__ wQd, ushort* __restrict__ wkT,
    float* __restrict__ wAlT, float* __restrict__ wScl,
    const float* __restrict__ o_w, ushort* __restrict__ owT) {
  __shared__ __attribute__((aligned(16))) char smem[77312];

  const int bid = blockIdx.x;
  const int tid = threadIdx.x;

  if (bid >= 512) {
    // ---- o_wT[h][d][v] bf16 path (24 blocks); uses 33.8 KB of smem
    const int b2 = bid - 512;
    const int h2 = b2 >> 2;
    const int db = (b2 & 3) * 64;
    ushort* t = (ushort*)smem;  // [64][264]
#pragma unroll
    for (int it = 0; it < 16; ++it) {
      const int v2 = it * 16 + (tid >> 4);
      const int dl = 4 * (tid & 15);
      const float4 x =
          *(const float4*)&o_w[((size_t)h2 * 256 + v2) * 256 + db + dl];
      t[(dl + 0) * 264 + v2] = (ushort)rnebf(x.x);
      t[(dl + 1) * 264 + v2] = (ushort)rnebf(x.y);
      t[(dl + 2) * 264 + v2] = (ushort)rnebf(x.z);
      t[(dl + 3) * 264 + v2] = (ushort)rnebf(x.w);
    }
    __syncthreads();
#pragma unroll
    for (int it = 0; it < 8; ++it) {
      const int idx = it * 256 + tid;
      const int d = idx >> 5;
      const int vv = (idx & 31) * 8;
      uint4 o;
      o.x = *(uint*)&t[d * 264 + vv + 0]; o.y = *(uint*)&t[d * 264 + vv + 2];
      o.z = *(uint*)&t[d * 264 + vv + 4]; o.w = *(uint*)&t[d * 264 + vv + 6];
      *(uint4*)&owT[((size_t)h2 * 256 + db + d) * 256 + vv] = o;
    }
    return;
  }

  const int bhx = bid & 15;
  if (bhx >= B_ * H_) return;
  const int nc = bid >> 4;
  const int bh = bhx;
  const int b = bh / H_, h = bh - b * H_;
  const int w = tid >> 6, l = tid & 63;
  const int lg = l >> 4, c16 = l & 15;
  const int cidx = bh * NC_ + nc;

  ushort* knB = (ushort*)smem;                   // 32K  (RAW k bf16)
  ushort* qnB = (ushort*)(smem + 32768);         // 32K  (RAW q bf16)
  ushort* Msc = (ushort*)(smem + 65536);         // [64][72] 9216 B
  float* bG = (float*)(smem + 74752);
  float* bB = bG + 64;
  float* bSc = bG + 128;
  float* bWl = bG + 192;
  float* bKg = bG + 256;
  float* bQg = bG + 320;
  float* bSk = bG + 384;
  float* bSq = bG + 448;
  float* bQe = bG + 512;

  const size_t srow0 = ((size_t)b * T_ + nc * C_) * H_ + h;
  if (tid < C_) {
    bG[tid] = Gc[cidx * C_ + tid];
    bB[tid] = beta[srow0 + (size_t)tid * H_];
  }
  __syncthreads();

  // ---- stage RAW q/k (bf16, XOR-swizzled rows of 512 B)
#pragma unroll
  for (int rr = 0; rr < 16; ++rr) {
    const int row = rr * 4 + w;
    const size_t g0 = (srow0 + (size_t)row * H_) * DK_;
    const float4 kv = *(const float4*)(k + g0 + 4 * l);
    const float4 qv = *(const float4*)(q + g0 + 4 * l);
    const int boff = row * 512 + ((8 * l) ^ ((row & 7) << 4));
    uint2 pk_, pq_;
    pk_.x = pkbf(kv.x, kv.y); pk_.y = pkbf(kv.z, kv.w);
    pq_.x = pkbf(qv.x, qv.y); pq_.y = pkbf(qv.z, qv.w);
    *(uint2*)((char*)knB + boff) = pk_;
    *(uint2*)((char*)qnB + boff) = pq_;
  }
  __syncthreads();

  // ---- MFMA: Mraw = q.k^T (32), Araw = k.k^T (32), Qdiag (8)
  f32x4 accm[4], acca[4];
  {
    const int xorv = (c16 & 7) << 4;
    const int rowA = 16 * w + c16;
    uint4 aq[8], ak[8];
#pragma unroll
    for (int kt = 0; kt < 8; ++kt) {
      const int coff = (64 * kt + 16 * lg) ^ xorv;
      aq[kt] = *(const uint4*)((char*)qnB + rowA * 512 + coff);
      ak[kt] = *(const uint4*)((char*)knB + rowA * 512 + coff);
    }
#pragma unroll
    for (int nt = 0; nt < 4; ++nt) {
      accm[nt] = (f32x4){0.f, 0.f, 0.f, 0.f};
      acca[nt] = (f32x4){0.f, 0.f, 0.f, 0.f};
    }
    f32x4 accq = (f32x4){0.f, 0.f, 0.f, 0.f};
#pragma unroll
    for (int nt = 0; nt < 4; ++nt) {
      const int rowB = 16 * nt + c16;
#pragma unroll
      for (int kt = 0; kt < 8; ++kt) {
        const uint4 bk =
            *(const uint4*)((char*)knB + rowB * 512 + ((64 * kt + 16 * lg) ^ xorv));
        const short8 bkf = u4_to_s8(bk);
        accm[nt] = __builtin_amdgcn_mfma_f32_16x16x32_bf16(u4_to_s8(aq[kt]),
                                                           bkf, accm[nt], 0, 0, 0);
        acca[nt] = __builtin_amdgcn_mfma_f32_16x16x32_bf16(u4_to_s8(ak[kt]),
                                                           bkf, acca[nt], 0, 0, 0);
      }
    }
#pragma unroll
    for (int kt = 0; kt < 8; ++kt) {
      const short8 bq = u4_to_s8(aq[kt]);
      accq = __builtin_amdgcn_mfma_f32_16x16x32_bf16(bq, bq, accq, 0, 0, 0);
    }
    // diag extraction: lanes with c16>>2 == lg hold t = 16w + c16 at r=c16&3
#pragma unroll
    for (int r = 0; r < 4; ++r) {
      if ((c16 >> 2) == lg && (c16 & 3) == r) {
        bKg[16 * w + c16] = acca[w][r];
        bQg[16 * w + c16] = accq[r];
      }
    }
  }
  __syncthreads();

  // ---- scalar pass: sq/sk + folded scales
  if (tid < C_) {
    const float gv = bG[tid];
    const float gend = bG[C_ - 1];
    const float skv = rsqrtf(bKg[tid] + 1e-6f);
    const float sqv = rsqrtf(bQg[tid] + 1e-6f) * 0.0625f;
    bSk[tid] = skv;
    bSq[tid] = sqv;
    bSc[tid] = __expf(gend - gv) * skv;
    bWl[tid] = bB[tid] * __expf(gv) * skv;
    bQe[tid] = sqv * __expf(gv);
  }
  __syncthreads();

  // ---- masks + scale + scatter: Msc (LDS), AlT -> GLOBAL fp32 [i][t]
  {
    float* gA = wAlT + (size_t)cidx * 4096;
#pragma unroll
    for (int nt = 0; nt < 4; ++nt) {
#pragma unroll
      for (int r = 0; r < 4; ++r) {
        const int t = 16 * w + 4 * lg + r;
        const int i = 16 * nt + c16;
        const float eg = __expf(bG[t] - bG[i]);
        const float ski = bSk[i];
        Msc[t * 72 + i] =
            (ushort)((i <= t) ? rnebf(accm[nt][r] * bSq[t] * ski * eg) : 0u);
        gA[i * 64 + t] =
            (i < t) ? bB[t] * bSk[t] * ski * eg * acca[nt][r] : 0.f;
      }
    }
  }
  // ---- column pass (thread = column d): kT emit + PRE-FS W store (bf16)
  {
    const int d = tid;
    ushort* wb = wWp + (size_t)cidx * C_ * 256;
#pragma unroll
    for (int e = 0; e < 8; ++e) {
      float vj[8];
#pragma unroll
      for (int j = 0; j < 8; ++j) {
        const int t = 8 * e + j;
        const float kv = bf2f(*(const ushort*)((char*)knB + t * 512 +
                                               ((2 * d) ^ ((t & 7) << 4))));
        vj[j] = kv;
        wb[t * 256 + d] = (ushort)rnebf(kv * bWl[t]);
      }
      uint4 o;
      o.x = pkbf(vj[0] * bSc[8 * e + 0], vj[1] * bSc[8 * e + 1]);
      o.y = pkbf(vj[2] * bSc[8 * e + 2], vj[3] * bSc[8 * e + 3]);
      o.z = pkbf(vj[4] * bSc[8 * e + 4], vj[5] * bSc[8 * e + 5]);
      o.w = pkbf(vj[6] * bSc[8 * e + 6], vj[7] * bSc[8 * e + 7]);
      *(uint4*)&wkT[((size_t)cidx * 256 + d) * C_ + 8 * e] = o;
    }
  }
  // ---- Qd emit: Qd = q_raw * sq * exp(G)
#pragma unroll
  for (int rr = 0; rr < 16; ++rr) {
    const int row = rr * 4 + w;
    const float qe = bQe[row];
    const uint2 pq =
        *(const uint2*)((char*)qnB + row * 512 + ((8 * l) ^ ((row & 7) << 4)));
    const float q0 = bf2f(pq.x), q1 = bf2f(pq.x >> 16);
    const float q2 = bf2f(pq.y), q3 = bf2f(pq.y >> 16);
    uint2 oq;
    oq.x = pkbf(q0 * qe, q1 * qe);
    oq.y = pkbf(q2 * qe, q3 * qe);
    *(uint2*)&wQd[(srow0 + (size_t)row * H_) * DK_ + 4 * l] = oq;
  }
  __syncthreads();  // Msc writes visible

  // ---- M store (vectorized from Msc)
  {
    const int row = tid >> 2;
#pragma unroll
    for (int e = 0; e < 2; ++e) {
      const int col = ((tid & 3) * 2 + e) * 8;
      *(uint4*)&wMp[(size_t)cidx * C_ * C_ + row * C_ + col] =
          *(const uint4*)&Msc[row * 72 + col];
    }
  }
  (void)wScl;
}

// ---------------------------------------------------------------------------
// Kernel 3b (parallel, register-heavy phase): forward substitution.
// (R20-proven) LDS 17.7 KB, single-pass dual FS in registers.
// ---------------------------------------------------------------------------
__global__ __launch_bounds__(256) void gdn_prep_fs_kernel(
    const float* __restrict__ v, const float* __restrict__ beta,
    const float* __restrict__ wAlT, ushort* __restrict__ wWp,
    uint2* __restrict__ wUp) {
  __shared__ __attribute__((aligned(16))) float AlT[64 * 68];
  __shared__ float bB[64];

  const int slot = blockIdx.x;
  const int bhx = slot & 15;
  if (bhx >= B_ * H_) return;
  const int nc = slot >> 4;
  const int bh = bhx;
  const int b = bh / H_, h = bh - b * H_;
  const int tid = threadIdx.x;
  const int cidx = bh * NC_ + nc;
  const size_t srow0 = ((size_t)b * T_ + nc * C_) * H_ + h;

  // stage AlT [64][64] global -> [64][68] LDS (coalesced)
  {
    const float* gA = wAlT + (size_t)cidx * 4096;
#pragma unroll
    for (int it = 0; it < 16; ++it) {
      const int idx = it * 256 + tid;
      AlT[(idx >> 6) * 68 + (idx & 63)] = gA[idx];
    }
  }
  if (tid < C_) bB[tid] = beta[srow0 + (size_t)tid * H_];
  __syncthreads();

  // ---- xw init: pre-FS W from wWp (coalesced bf16 column read)
  float xw[64];
  ushort* wb = wWp + (size_t)cidx * C_ * 256;
#pragma unroll
  for (int t = 0; t < C_; ++t) xw[t] = bf2f(wb[t * 256 + tid]);

  // ---- xu init: beta*V, coalesced column read
  float xu[64];
#pragma unroll
  for (int t = 0; t < C_; ++t)
    xu[t] = v[(srow0 + (size_t)t * H_) * DV_ + tid] * bB[t];

  // ---- forward substitution IN REGISTERS (AlT broadcast reads only)
#pragma unroll
  for (int tb = 0; tb < 8; ++tb) {
#pragma unroll
    for (int i = 0; i < 8 * tb; ++i) {
      const float xui = xu[i];
      const float xwi = xw[i];
      float av[8];
      *(float4*)&av[0] = *(float4*)&AlT[i * 68 + 8 * tb];
      *(float4*)&av[4] = *(float4*)&AlT[i * 68 + 8 * tb + 4];
#pragma unroll
      for (int e = 0; e < 8; ++e) {
        xu[8 * tb + e] = fmaf(-av[e], xui, xu[8 * tb + e]);
        xw[8 * tb + e] = fmaf(-av[e], xwi, xw[8 * tb + e]);
      }
    }
#pragma unroll
    for (int e = 1; e < 8; ++e)
#pragma unroll
      for (int m = 0; m < 7; ++m)
        if (m < e) {
          const float am = AlT[(8 * tb + m) * 68 + 8 * tb + e];
          xu[8 * tb + e] = fmaf(-am, xu[8 * tb + m], xu[8 * tb + e]);
          xw[8 * tb + e] = fmaf(-am, xw[8 * tb + m], xw[8 * tb + e]);
        }
  }
  // ---- store W (bf16 row-major, coalesced) and U (C/D-fragment pairs)
  {
#pragma unroll
    for (int row = 0; row < C_; ++row)
      wb[row * 256 + tid] = (ushort)rnebf(xw[row]);
    const int cbw = tid >> 4, c16s = tid & 15;
#pragma unroll
    for (int mt = 0; mt < 4; ++mt) {
#pragma unroll
      for (int lgi = 0; lgi < 4; ++lgi) {
        const int r0 = 16 * mt + 4 * lgi;
        uint2 val;
        val.x = pkbf(xu[r0 + 0], xu[r0 + 1]);
        val.y = pkbf(xu[r0 + 2], xu[r0 + 3]);
        wUp[(((size_t)cidx * 16 + cbw) * 4 + mt) * 64 + (lgi << 4) + c16s] = val;
      }
    }
  }
}

// ---------------------------------------------------------------------------
// Kernel 4 (sequential, MFMA, 4-way k-split): grid 256 = cb*16 + bh
// (XCD = bh%8); 4 waves per block (256 thr): wave kh owns S rows
// kh*64..+63 for col-block cb (S = 4 f32x4). GEMM1 partial p summed
// 4-way via LDS. Per-wave work halved vs 2-way split.
// ---------------------------------------------------------------------------
__global__ __launch_bounds__(256, 1) void gdn_seq_kernel(
    const ushort* __restrict__ wkT, const ushort* __restrict__ wWp,
    const uint2* __restrict__ wUp, const float* __restrict__ lam,
    uint2* __restrict__ wDP, uint2* __restrict__ wSP) {
  const int bid = blockIdx.x;
  const int cb = bid >> 4, bhx = bid & 15;
  if (bhx >= B_ * H_) return;
  const int bh = bhx;
  const int tid = threadIdx.x;
  const int kh = tid >> 6, l = tid & 63;
  const int lg = l >> 4, c16 = l & 15;
  const int xorv = (c16 & 7) << 4;

  __shared__ ushort sW[2][16384];
  __shared__ ushort sK[2][16384];
  __shared__ uint2 sU[2][256];
  __shared__ f32x4 sX[4][4][64];
  __shared__ float sLam[NC_];

  // ---- staging: each wave issues exactly 17 global_load_lds per chunk
  auto stage = [&](int pp, int cidx2) {
    const char* gw_ = (const char*)(wWp + (size_t)cidx2 * 16384);
#pragma unroll
    for (int j = 0; j < 8; ++j) {
      const int i = kh * 8 + j;
      const int row = 2 * i + (l >> 5);
      const int colb = ((l & 31) * 16) ^ ((row & 7) << 4);
      gload_lds16(gw_ + row * 512 + colb, (char*)&sW[pp][0] + i * 1024);
    }
    const char* gk_ = (const char*)(wkT + (size_t)cidx2 * 16384);
#pragma unroll
    for (int j = 0; j < 8; ++j) {
      const int i = kh * 8 + j;
      const int row = 8 * i + (l >> 3);
      const int colb = ((l & 7) * 16) ^ ((row & 7) << 4);
      gload_lds16(gk_ + row * 128 + colb, (char*)&sK[pp][0] + i * 1024);
    }
    // U: 2 segments; waves {0,2} load seg0, {1,3} load seg1 (dup, benign)
    const char* gu_ = (const char*)wUp + ((size_t)cidx2 * 16 + cb) * 2048;
    const int iu = kh & 1;
    gload_lds16(gu_ + iu * 1024 + l * 16, (char*)&sU[pp][0] + iu * 1024);
  };

  f32x4 S[4];
#pragma unroll
  for (int m2 = 0; m2 < 4; ++m2) S[m2] = (f32x4){0.f, 0.f, 0.f, 0.f};

  stage(0, bh * NC_ + 0);
  stage(1, bh * NC_ + 1);
  if (tid < NC_) sLam[tid] = lam[bh * NC_ + tid];
  asm volatile("s_waitcnt lgkmcnt(0)" ::: "memory");
  __builtin_amdgcn_sched_barrier(0);
  __builtin_amdgcn_s_barrier();
  __builtin_amdgcn_sched_barrier(0);

  for (int nc = 0; nc < NC_; ++nc) {
    const int pp = nc & 1;
    const int cidx = bh * NC_ + nc;
    // per-wave newest outstanding: nc=0 -> stage(1)=17; steady -> prev
    // stores(3) + next stage(17) = 20; last -> 3.
    if (nc == 0)
      asm volatile("s_waitcnt vmcnt(17)" ::: "memory");
    else if (nc == NC_ - 1)
      asm volatile("s_waitcnt vmcnt(3)" ::: "memory");
    else
      asm volatile("s_waitcnt vmcnt(20)" ::: "memory");
    __builtin_amdgcn_sched_barrier(0);
    __builtin_amdgcn_s_barrier();
    __builtin_amdgcn_sched_barrier(0);

    // pack this k-quarter's S -> P (4 mtiles); store checkpoint (2 dwordx4)
    uint2 P[4];
#pragma unroll
    for (int m2 = 0; m2 < 4; ++m2) {
      P[m2].x = pkbf(S[m2][0], S[m2][1]);
      P[m2].y = pkbf(S[m2][2], S[m2][3]);
    }
    {
      uint4* sp4 = (uint4*)(wSP + (((size_t)cidx * 16 + cb) * 64 + l) * 16 +
                            kh * 4);
      uint4 o0; o0.x = P[0].x; o0.y = P[0].y; o0.z = P[1].x; o0.w = P[1].y;
      uint4 o1; o1.x = P[2].x; o1.y = P[2].y; o1.z = P[3].x; o1.w = P[3].y;
      sp4[0] = o0; sp4[1] = o1;
    }

    // GEMM1 partial: p = W[:, kquarter] * S[kquarter]  (2 kt-tiles, 8 MFMA)
    f32x4 pe[4], po[4];
#pragma unroll
    for (int mt = 0; mt < 4; ++mt) {
      pe[mt] = (f32x4){0.f, 0.f, 0.f, 0.f};
      po[mt] = (f32x4){0.f, 0.f, 0.f, 0.f};
    }
    const char* sWb = (const char*)&sW[pp][0];
#pragma unroll
    for (int ktl = 0; ktl < 2; ++ktl) {
      const int kt = kh * 2 + ktl;
      const short8 Bf = buildB(P[2 * ktl], P[2 * ktl + 1], lg, c16);
      const int colb = (64 * kt + 16 * lg) ^ xorv;
#pragma unroll
      for (int mt = 0; mt < 4; ++mt) {
        const uint4 aw = *(const uint4*)(sWb + (16 * mt + c16) * 512 + colb);
        if (ktl & 1)
          po[mt] = __builtin_amdgcn_mfma_f32_16x16x32_bf16(u4_to_s8(aw), Bf,
                                                           po[mt], 0, 0, 0);
        else
          pe[mt] = __builtin_amdgcn_mfma_f32_16x16x32_bf16(u4_to_s8(aw), Bf,
                                                           pe[mt], 0, 0, 0);
      }
    }
#pragma unroll
    for (int mt = 0; mt < 4; ++mt) sX[kh][mt][l] = pe[mt] + po[mt];
    asm volatile("s_waitcnt lgkmcnt(0)" ::: "memory");
    __builtin_amdgcn_sched_barrier(0);
    __builtin_amdgcn_s_barrier();
    __builtin_amdgcn_sched_barrier(0);

    // delta = U - (sum of 4 partials); identical on all waves
    uint2 DP[4];
#pragma unroll
    for (int mt = 0; mt < 4; ++mt) {
      const f32x4 p0 = sX[0][mt][l];
      const f32x4 p1 = sX[1][mt][l];
      const f32x4 p2 = sX[2][mt][l];
      const f32x4 p3 = sX[3][mt][l];
      const uint2 uu = sU[pp][mt * 64 + l];
      const float d0 = bf2f(uu.x) - ((p0[0] + p1[0]) + (p2[0] + p3[0]));
      const float d1 = bf2f(uu.x >> 16) - ((p0[1] + p1[1]) + (p2[1] + p3[1]));
      const float d2 = bf2f(uu.y) - ((p0[2] + p1[2]) + (p2[2] + p3[2]));
      const float d3 = bf2f(uu.y >> 16) - ((p0[3] + p1[3]) + (p2[3] + p3[3]));
      DP[mt].x = pkbf(d0, d1);
      DP[mt].y = pkbf(d2, d3);
    }
    {
      // store split: waves {0,2} -> DP[0..1], waves {1,3} -> DP[2..3]
      // (duplicate same-value stores equalize per-wave vmem counts)
      uint4* dp4 = (uint4*)(wDP + (((size_t)cidx * 16 + cb) * 64 + l) * 4);
      uint4 od;
      if ((kh & 1) == 0) { od.x = DP[0].x; od.y = DP[0].y; od.z = DP[1].x; od.w = DP[1].y; }
      else               { od.x = DP[2].x; od.y = DP[2].y; od.z = DP[3].x; od.w = DP[3].y; }
      dp4[kh & 1] = od;
    }
    // S = lamC*S + kT[kquarter rows] * delta
    const float lamC = sLam[nc];
#pragma unroll
    for (int m2 = 0; m2 < 4; ++m2) {
      S[m2][0] *= lamC; S[m2][1] *= lamC; S[m2][2] *= lamC; S[m2][3] *= lamC;
    }
    const char* sKb = (const char*)&sK[pp][0];
#pragma unroll
    for (int kt2 = 0; kt2 < 2; ++kt2) {
      const short8 Bd = buildB(DP[2 * kt2], DP[2 * kt2 + 1], lg, c16);
      const int colb = (64 * kt2 + 16 * lg) ^ xorv;
#pragma unroll
      for (int m2 = 0; m2 < 4; ++m2) {
        const int m2g = kh * 4 + m2;
        const uint4 ak = *(const uint4*)(sKb + (16 * m2g + c16) * 128 + colb);
        S[m2] = __builtin_amdgcn_mfma_f32_16x16x32_bf16(u4_to_s8(ak), Bd,
                                                        S[m2], 0, 0, 0);
      }
    }
    // all waves done reading buf[pp] -> safe to restage it
    __builtin_amdgcn_sched_barrier(0);
    __builtin_amdgcn_s_barrier();
    __builtin_amdgcn_sched_barrier(0);
    if (nc + 2 < NC_) stage(pp, cidx + 2);
    __builtin_amdgcn_sched_barrier(0);
  }
}

// ---------------------------------------------------------------------------
// Kernel 5 (parallel, MFMA, fused epilogue): grid 512 = nc*16 + bh.
// ---------------------------------------------------------------------------
__global__ __launch_bounds__(256) void gdn_ofin_kernel(
    const ushort* __restrict__ wQd, const ushort* __restrict__ wMp,
    const uint2* __restrict__ wDP, const uint2* __restrict__ wSP,
    const float* __restrict__ sgate, const float* __restrict__ norm_w,
    const ushort* __restrict__ owT, float* __restrict__ out) {
  const int slot = blockIdx.x;
  const int bhx = slot & 15;
  if (bhx >= B_ * H_) return;
  const int nc = slot >> 4;
  const int bh = bhx;
  const int cidx = bh * NC_ + nc;
  const int b = bh / H_, h = bh - b * H_;
  const int tid = threadIdx.x;
  const int w = tid >> 6, l = tid & 63;
  const int lg = l >> 4, c16 = l & 15;
  const size_t t0 = (size_t)b * T_ + nc * C_;

  __shared__ ushort onl[64 * 256];
  __shared__ float red[64][4];
  __shared__ float rowf[64];

  f32x4 acc[4][4];
#pragma unroll
  for (int mt = 0; mt < 4; ++mt)
#pragma unroll
    for (int nt = 0; nt < 4; ++nt) acc[mt][nt] = (f32x4){0.f, 0.f, 0.f, 0.f};

#pragma unroll
  for (int nt = 0; nt < 4; ++nt) {
    const int cbwq = 4 * w + nt;
    uint2 SPl[16];
    const uint4* sp4 =
        (const uint4*)(wSP + (((size_t)cidx * 16 + cbwq) * 64 + l) * 16);
#pragma unroll
    for (int i = 0; i < 8; ++i) {
      const uint4 t4 = sp4[i];
      SPl[2 * i].x = t4.x; SPl[2 * i].y = t4.y;
      SPl[2 * i + 1].x = t4.z; SPl[2 * i + 1].y = t4.w;
    }
#pragma unroll
    for (int kt = 0; kt < 8; ++kt) {
      const short8 Bf = buildB(SPl[2 * kt], SPl[2 * kt + 1], lg, c16);
#pragma unroll
      for (int mt = 0; mt < 4; ++mt) {
        const uint4 aq = *(const uint4*)&wQd[((t0 + 16 * mt + c16) * H_ + h) *
                                                 (size_t)DK_ +
                                             32 * kt + 8 * lg];
        acc[mt][nt] = __builtin_amdgcn_mfma_f32_16x16x32_bf16(
            u4_to_s8(aq), Bf, acc[mt][nt], 0, 0, 0);
      }
    }
  }
  const ushort* Mb = wMp + (size_t)cidx * C_ * C_;
#pragma unroll
  for (int nt = 0; nt < 4; ++nt) {
    const int cbwq = 4 * w + nt;
    uint2 DPl[4];
    {
      const uint4* dp4 =
          (const uint4*)(wDP + (((size_t)cidx * 16 + cbwq) * 64 + l) * 4);
      const uint4 a0 = dp4[0], a1 = dp4[1];
      DPl[0].x = a0.x; DPl[0].y = a0.y; DPl[1].x = a0.z; DPl[1].y = a0.w;
      DPl[2].x = a1.x; DPl[2].y = a1.y; DPl[3].x = a1.z; DPl[3].y = a1.w;
    }
#pragma unroll
    for (int kt2 = 0; kt2 < 2; ++kt2) {
      const short8 Bf = buildB(DPl[2 * kt2], DPl[2 * kt2 + 1], lg, c16);
#pragma unroll
      for (int mt = 0; mt < 4; ++mt) {
        const uint4 am =
            *(const uint4*)&Mb[(16 * mt + c16) * C_ + 32 * kt2 + 8 * lg];
        acc[mt][nt] = __builtin_amdgcn_mfma_f32_16x16x32_bf16(
            u4_to_s8(am), Bf, acc[mt][nt], 0, 0, 0);
      }
    }
  }

  float ss[4][4];
#pragma unroll
  for (int mt = 0; mt < 4; ++mt)
#pragma unroll
    for (int r = 0; r < 4; ++r) {
      float s = acc[mt][0][r] * acc[mt][0][r];
      s = fmaf(acc[mt][1][r], acc[mt][1][r], s);
      s = fmaf(acc[mt][2][r], acc[mt][2][r], s);
      s = fmaf(acc[mt][3][r], acc[mt][3][r], s);
      s += __shfl_xor(s, 1);
      s += __shfl_xor(s, 2);
      s += __shfl_xor(s, 4);
      s += __shfl_xor(s, 8);
      ss[mt][r] = s;
    }
  if (c16 == 0) {
#pragma unroll
    for (int mt = 0; mt < 4; ++mt)
#pragma unroll
      for (int r = 0; r < 4; ++r) red[16 * mt + 4 * lg + r][w] = ss[mt][r];
  }
  __syncthreads();
  if (tid < 64) {
    const float ms =
        (red[tid][0] + red[tid][1] + red[tid][2] + red[tid][3]) * (1.f / DV_);
    const float sg = sgate[(t0 + tid) * H_ + h];
    rowf[tid] = rsqrtf(ms + 1e-5f) * sg;
  }
  __syncthreads();

  {
    char* onb = (char*)onl;
#pragma unroll
    for (int mt = 0; mt < 4; ++mt) {
      float rf[4];
#pragma unroll
      for (int r = 0; r < 4; ++r) rf[r] = rowf[16 * mt + 4 * lg + r];
#pragma unroll
      for (int nt = 0; nt < 4; ++nt) {
        const int c = (4 * w + nt) * 16 + c16;
        const float nwv = norm_w[c];
#pragma unroll
        for (int r = 0; r < 4; ++r) {
          const int row = 16 * mt + 4 * lg + r;
          const float v = acc[mt][nt][r] * rf[r] * nwv;
          *(ushort*)(onb + row * 512 + ((2 * c) ^ ((row & 7) << 4))) =
              (ushort)rnebf(v);
        }
      }
    }
  }
  __syncthreads();

  f32x4 acc2[4][4];
#pragma unroll
  for (int mt = 0; mt < 4; ++mt)
#pragma unroll
    for (int nt2 = 0; nt2 < 4; ++nt2)
      acc2[mt][nt2] = (f32x4){0.f, 0.f, 0.f, 0.f};
  {
    const char* onb = (const char*)onl;
#pragma unroll
    for (int kt = 0; kt < 8; ++kt) {
      uint4 af[4];
#pragma unroll
      for (int mt = 0; mt < 4; ++mt)
        af[mt] = *(const uint4*)(onb + (16 * mt + c16) * 512 +
                                 ((64 * kt + 16 * lg) ^ ((c16 & 7) << 4)));
#pragma unroll
      for (int nt2 = 0; nt2 < 4; ++nt2) {
        const uint4 bf = *(const uint4*)&owT[((size_t)h * 256 +
                                              (4 * w + nt2) * 16 + c16) *
                                                 256 +
                                             32 * kt + 8 * lg];
#pragma unroll
        for (int mt = 0; mt < 4; ++mt)
          acc2[mt][nt2] = __builtin_amdgcn_mfma_f32_16x16x32_bf16(
              u4_to_s8(af[mt]), u4_to_s8(bf), acc2[mt][nt2], 0, 0, 0);
      }
    }
  }
#pragma unroll
  for (int mt = 0; mt < 4; ++mt)
#pragma unroll
    for (int nt2 = 0; nt2 < 4; ++nt2)
#pragma unroll
      for (int r = 0; r < 4; ++r)
        out[((t0 + 16 * mt + 4 * lg + r) * H_ + h) * (size_t)DK_ +
            (4 * w + nt2) * 16 + c16] = acc2[mt][nt2][r];
}

// ---------------------------------------------------------------------------
extern "C" void kernel_launch(void* const* d_in, const int* in_sizes, int n_in,
                              void* d_out, int out_size, void* d_ws,
                              size_t ws_size, hipStream_t stream) {
  const float* hab = (const float*)d_in[0];
  const float* hg = (const float*)d_in[1];
  const float* q = (const float*)d_in[2];
  const float* k = (const float*)d_in[3];
  const float* v = (const float*)d_in[4];
  const float* b_w = (const float*)d_in[5];
  const float* a_w = (const float*)d_in[6];
  const float* A_log = (const float*)d_in[7];
  const float* dt_bias = (const float*)d_in[8];
  const float* g_w = (const float*)d_in[9];
  const float* norm_w = (const float*)d_in[10];
  const float* o_w = (const float*)d_in[11];
  float* out = (float*)d_out;

  float* ws = (float*)d_ws;
  const size_t NBT = (size_t)B_ * T_ * H_;  // 24576
  float* w_beta = ws;
  float* w_g = ws + NBT;
  float* w_sg = ws + 2 * NBT;
  float* w_G = ws + 5 * NBT;
  float* w_lam = ws + 7 * NBT;                     // B*H*NC = 384 (pad 1024)
  ushort* w_Qd = (ushort*)(ws + 7 * NBT + 1024);   // 12,582,912 u16
  ushort* w_kT = w_Qd + (size_t)12582912;          // 6,291,456 u16
  ushort* w_W = w_kT + (size_t)6291456;            // 6,291,456 u16
  ushort* w_M = w_W + (size_t)6291456;             // 1,572,864 u16
  uint2* w_U = (uint2*)(w_M + (size_t)1572864);    // 1,572,864 uint2
  uint2* w_DP = w_U + (size_t)1572864;             // 1,572,864 uint2
  uint2* w_SP = w_DP + (size_t)1572864;            // 6,291,456 uint2
  ushort* w_owT = (ushort*)(w_SP + (size_t)6291456);  // 393,216 u16
  float* w_AlT = (float*)(w_owT + (size_t)393216);    // 1,572,864 f32

  hipLaunchKernelGGL(gdn_proj_kernel, dim3(B_ * T_), dim3(256), 0, stream,
                     hab, hg, b_w, a_w, g_w, A_log, dt_bias, w_beta, w_g,
                     w_sg);
  hipLaunchKernelGGL(gdn_cum_kernel, dim3(B_ * H_), dim3(256), 0, stream,
                     w_g, w_G, w_lam);
  hipLaunchKernelGGL(gdn_prep_mfma_kernel, dim3(512 + 24), dim3(256), 0,
                     stream, q, k, w_beta, w_G, w_W, w_M, w_Qd, w_kT, w_AlT,
                     nullptr, o_w, w_owT);
  hipLaunchKernelGGL(gdn_prep_fs_kernel, dim3(512), dim3(256), 0, stream,
                     v, w_beta, w_AlT, w_W, w_U);
  hipLaunchKernelGGL(gdn_seq_kernel, dim3(256), dim3(256), 0, stream,
                     w_kT, w_W, w_U, w_lam, w_DP, w_SP);
  hipLaunchKernelGGL(gdn_ofin_kernel, dim3(512), dim3(256), 0, stream,
                     w_Qd, w_M, w_DP, w_SP, w_sg, norm_w, w_owT, out);
}

// Round 22
// 250.655 us; speedup vs baseline: 1.0709x; 1.0709x over previous
//
#include <hip/hip_runtime.h>
#include <hip/hip_bf16.h>
#include <math.h>

#define B_ 2
#define T_ 2048
#define H_ 6
#define DK_ 256
#define DV_ 256
#define HID_ 2048
#define C_ 64
#define NC_ 32

typedef __attribute__((ext_vector_type(8))) short short8;
typedef __attribute__((ext_vector_type(4))) float f32x4;

__device__ __forceinline__ unsigned rnebf(float f) {
  unsigned u = __float_as_uint(f);
  return (u + 0x7fffu + ((u >> 16) & 1u)) >> 16;
}
__device__ __forceinline__ unsigned pkbf(float lo, float hi) {
  return rnebf(lo) | (rnebf(hi) << 16);
}
__device__ __forceinline__ float bf2f(unsigned u16v) {
  return __uint_as_float((u16v & 0xffffu) << 16);
}
__device__ __forceinline__ short8 u4_to_s8(uint4 u) {
  union { uint4 u; short8 s; } c; c.u = u; return c.s;
}

// async global->LDS 16B per lane; LDS dest wave-uniform base + lane*16
__device__ __forceinline__ void gload_lds16(const void* g, void* l) {
  __builtin_amdgcn_global_load_lds(
      (const __attribute__((address_space(1))) unsigned int*)g,
      (__attribute__((address_space(3))) unsigned int*)l, 16, 0, 0);
}

// Build MFMA B-fragment (16x16x32 bf16) for a k-tile from two C/D-layout
// packed mtiles Pe (even 16 rows) and Po (odd 16 rows).
__device__ __forceinline__ short8 buildB(uint2 Pe, uint2 Po, int lg, int c16) {
  const int src0 = ((2 * (lg & 1)) << 4) | c16;
  const int src1 = src0 + 16;
  int e0 = __shfl((int)Pe.x, src0), o0 = __shfl((int)Po.x, src0);
  int e1 = __shfl((int)Pe.y, src0), o1 = __shfl((int)Po.y, src0);
  int e2 = __shfl((int)Pe.x, src1), o2 = __shfl((int)Po.x, src1);
  int e3 = __shfl((int)Pe.y, src1), o3 = __shfl((int)Po.y, src1);
  const bool lo2 = (lg < 2);
  union { int i[4]; short8 s; } u;
  u.i[0] = lo2 ? e0 : o0;
  u.i[1] = lo2 ? e1 : o1;
  u.i[2] = lo2 ? e2 : o2;
  u.i[3] = lo2 ? e3 : o3;
  return u.s;
}

// ---------------------------------------------------------------------------
// Kernel 1: fused projections only
// ---------------------------------------------------------------------------
__global__ __launch_bounds__(256) void gdn_proj_kernel(
    const float* __restrict__ hab, const float* __restrict__ hg,
    const float* __restrict__ b_w, const float* __restrict__ a_w,
    const float* __restrict__ g_w, const float* __restrict__ A_log,
    const float* __restrict__ dt_bias,
    float* __restrict__ beta_o, float* __restrict__ g_o,
    float* __restrict__ sgate_o) {
  const int bt = blockIdx.x;
  const int tid = threadIdx.x;
  const int lane = tid & 63;
  const int wid = tid >> 6;

  const float* h1 = hab + (size_t)bt * HID_ + tid * 8;
  const float* h2 = hg + (size_t)bt * HID_ + tid * 8;
  const float4 xa = *(const float4*)(h1);
  const float4 xb = *(const float4*)(h1 + 4);
  const float4 ya = *(const float4*)(h2);
  const float4 yb = *(const float4*)(h2 + 4);

  float part[18];
#pragma unroll
  for (int n = 0; n < 6; ++n) {
    const float* wp = b_w + n * HID_ + tid * 8;
    const float4 w0 = *(const float4*)(wp);
    const float4 w1 = *(const float4*)(wp + 4);
    part[n] = xa.x * w0.x + xa.y * w0.y + xa.z * w0.z + xa.w * w0.w +
              xb.x * w1.x + xb.y * w1.y + xb.z * w1.z + xb.w * w1.w;
  }
#pragma unroll
  for (int n = 0; n < 6; ++n) {
    const float* wp = a_w + n * HID_ + tid * 8;
    const float4 w0 = *(const float4*)(wp);
    const float4 w1 = *(const float4*)(wp + 4);
    part[6 + n] = xa.x * w0.x + xa.y * w0.y + xa.z * w0.z + xa.w * w0.w +
                  xb.x * w1.x + xb.y * w1.y + xb.z * w1.z + xb.w * w1.w;
  }
#pragma unroll
  for (int n = 0; n < 6; ++n) {
    const float* wp = g_w + n * HID_ + tid * 8;
    const float4 w0 = *(const float4*)(wp);
    const float4 w1 = *(const float4*)(wp + 4);
    part[12 + n] = ya.x * w0.x + ya.y * w0.y + ya.z * w0.z + ya.w * w0.w +
                   yb.x * w1.x + yb.y * w1.y + yb.z * w1.z + yb.w * w1.w;
  }

  __shared__ float red[18][4];
#pragma unroll
  for (int i = 0; i < 18; ++i) {
    float x = part[i];
    x += __shfl_xor(x, 1);
    x += __shfl_xor(x, 2);
    x += __shfl_xor(x, 4);
    x += __shfl_xor(x, 8);
    x += __shfl_xor(x, 16);
    x += __shfl_xor(x, 32);
    if (lane == 0) red[i][wid] = x;
  }
  __syncthreads();

  if (tid < 18) {
    const float s = red[tid][0] + red[tid][1] + red[tid][2] + red[tid][3];
    if (tid < 6) {
      beta_o[(size_t)bt * H_ + tid] = 1.f / (1.f + __expf(-s));
    } else if (tid < 12) {
      const int n = tid - 6;
      const float x = s + dt_bias[n];
      const float sp = (x > 20.f) ? x : log1pf(__expf(x));
      g_o[(size_t)bt * H_ + n] = -__expf(A_log[n]) * sp;
    } else {
      const int n = tid - 12;
      sgate_o[(size_t)bt * H_ + n] = s / (1.f + __expf(-s));
    }
  }
}

// ---------------------------------------------------------------------------
// Kernel 2: per-chunk inclusive cumsum of g; lam = exp(gend)
// ---------------------------------------------------------------------------
__global__ __launch_bounds__(256) void gdn_cum_kernel(
    const float* __restrict__ g, float* __restrict__ Gc,
    float* __restrict__ lam) {
  const int bh = blockIdx.x;
  const int b = bh / H_, h = bh - b * H_;
  const int w = threadIdx.x >> 6, l = threadIdx.x & 63;
  for (int it = 0; it < 8; ++it) {
    const int nc = it * 4 + w;
    const int tg = nc * C_ + l;
    const size_t srow = ((size_t)b * T_ + tg) * H_ + h;
    float val = g[srow];
#pragma unroll
    for (int ofs = 1; ofs < 64; ofs <<= 1) {
      const float o = __shfl_up(val, ofs);
      if (l >= ofs) val += o;
    }
    Gc[(bh * NC_ + nc) * C_ + l] = val;
    if (l == 63) lam[bh * NC_ + nc] = __expf(val);
  }
}

// ---------------------------------------------------------------------------
// Kernel 3a (parallel, LDS-heavy phase): stages RAW q/k bf16; M=q.k^T,
// A=k.k^T, diag -> sq/sk via MFMA; emits Qd, kT, M, PRE-FS W (kn*bWl, bf16)
// and AlT -> GLOBAL (fp32). LDS 75.3 KB -> 2 blocks/CU. (R20-proven)
// ---------------------------------------------------------------------------
__global__ __launch_bounds__(256) void gdn_prep_mfma_kernel(
    const float* __restrict__ q, const float* __restrict__ k,
    const float* __restrict__ beta, const float* __restrict__ Gc,
    ushort* __restrict__ wWp, ushort* __restrict__ wMp,
    ushort* __restrict__ wQd, ushort* __restrict__ wkT,
    float* __restrict__ wAlT, float* __restrict__ wScl,
    const float* __restrict__ o_w, ushort* __restrict__ owT) {
  __shared__ __attribute__((aligned(16))) char smem[77312];

  const int bid = blockIdx.x;
  const int tid = threadIdx.x;

  if (bid >= 512) {
    // ---- o_wT[h][d][v] bf16 path (24 blocks); uses 33.8 KB of smem
    const int b2 = bid - 512;
    const int h2 = b2 >> 2;
    const int db = (b2 & 3) * 64;
    ushort* t = (ushort*)smem;  // [64][264]
#pragma unroll
    for (int it = 0; it < 16; ++it) {
      const int v2 = it * 16 + (tid >> 4);
      const int dl = 4 * (tid & 15);
      const float4 x =
          *(const float4*)&o_w[((size_t)h2 * 256 + v2) * 256 + db + dl];
      t[(dl + 0) * 264 + v2] = (ushort)rnebf(x.x);
      t[(dl + 1) * 264 + v2] = (ushort)rnebf(x.y);
      t[(dl + 2) * 264 + v2] = (ushort)rnebf(x.z);
      t[(dl + 3) * 264 + v2] = (ushort)rnebf(x.w);
    }
    __syncthreads();
#pragma unroll
    for (int it = 0; it < 8; ++it) {
      const int idx = it * 256 + tid;
      const int d = idx >> 5;
      const int vv = (idx & 31) * 8;
      uint4 o;
      o.x = *(uint*)&t[d * 264 + vv + 0]; o.y = *(uint*)&t[d * 264 + vv + 2];
      o.z = *(uint*)&t[d * 264 + vv + 4]; o.w = *(uint*)&t[d * 264 + vv + 6];
      *(uint4*)&owT[((size_t)h2 * 256 + db + d) * 256 + vv] = o;
    }
    return;
  }

  const int bhx = bid & 15;
  if (bhx >= B_ * H_) return;
  const int nc = bid >> 4;
  const int bh = bhx;
  const int b = bh / H_, h = bh - b * H_;
  const int w = tid >> 6, l = tid & 63;
  const int lg = l >> 4, c16 = l & 15;
  const int cidx = bh * NC_ + nc;

  ushort* knB = (ushort*)smem;                   // 32K  (RAW k bf16)
  ushort* qnB = (ushort*)(smem + 32768);         // 32K  (RAW q bf16)
  ushort* Msc = (ushort*)(smem + 65536);         // [64][72] 9216 B
  float* bG = (float*)(smem + 74752);
  float* bB = bG + 64;
  float* bSc = bG + 128;
  float* bWl = bG + 192;
  float* bKg = bG + 256;
  float* bQg = bG + 320;
  float* bSk = bG + 384;
  float* bSq = bG + 448;
  float* bQe = bG + 512;

  const size_t srow0 = ((size_t)b * T_ + nc * C_) * H_ + h;
  if (tid < C_) {
    bG[tid] = Gc[cidx * C_ + tid];
    bB[tid] = beta[srow0 + (size_t)tid * H_];
  }
  __syncthreads();

  // ---- stage RAW q/k (bf16, XOR-swizzled rows of 512 B)
#pragma unroll
  for (int rr = 0; rr < 16; ++rr) {
    const int row = rr * 4 + w;
    const size_t g0 = (srow0 + (size_t)row * H_) * DK_;
    const float4 kv = *(const float4*)(k + g0 + 4 * l);
    const float4 qv = *(const float4*)(q + g0 + 4 * l);
    const int boff = row * 512 + ((8 * l) ^ ((row & 7) << 4));
    uint2 pk_, pq_;
    pk_.x = pkbf(kv.x, kv.y); pk_.y = pkbf(kv.z, kv.w);
    pq_.x = pkbf(qv.x, qv.y); pq_.y = pkbf(qv.z, qv.w);
    *(uint2*)((char*)knB + boff) = pk_;
    *(uint2*)((char*)qnB + boff) = pq_;
  }
  __syncthreads();

  // ---- MFMA: Mraw = q.k^T (32), Araw = k.k^T (32), Qdiag (8)
  f32x4 accm[4], acca[4];
  {
    const int xorv = (c16 & 7) << 4;
    const int rowA = 16 * w + c16;
    uint4 aq[8], ak[8];
#pragma unroll
    for (int kt = 0; kt < 8; ++kt) {
      const int coff = (64 * kt + 16 * lg) ^ xorv;
      aq[kt] = *(const uint4*)((char*)qnB + rowA * 512 + coff);
      ak[kt] = *(const uint4*)((char*)knB + rowA * 512 + coff);
    }
#pragma unroll
    for (int nt = 0; nt < 4; ++nt) {
      accm[nt] = (f32x4){0.f, 0.f, 0.f, 0.f};
      acca[nt] = (f32x4){0.f, 0.f, 0.f, 0.f};
    }
    f32x4 accq = (f32x4){0.f, 0.f, 0.f, 0.f};
#pragma unroll
    for (int nt = 0; nt < 4; ++nt) {
      const int rowB = 16 * nt + c16;
#pragma unroll
      for (int kt = 0; kt < 8; ++kt) {
        const uint4 bk =
            *(const uint4*)((char*)knB + rowB * 512 + ((64 * kt + 16 * lg) ^ xorv));
        const short8 bkf = u4_to_s8(bk);
        accm[nt] = __builtin_amdgcn_mfma_f32_16x16x32_bf16(u4_to_s8(aq[kt]),
                                                           bkf, accm[nt], 0, 0, 0);
        acca[nt] = __builtin_amdgcn_mfma_f32_16x16x32_bf16(u4_to_s8(ak[kt]),
                                                           bkf, acca[nt], 0, 0, 0);
      }
    }
#pragma unroll
    for (int kt = 0; kt < 8; ++kt) {
      const short8 bq = u4_to_s8(aq[kt]);
      accq = __builtin_amdgcn_mfma_f32_16x16x32_bf16(bq, bq, accq, 0, 0, 0);
    }
    // diag extraction: lanes with c16>>2 == lg hold t = 16w + c16 at r=c16&3
#pragma unroll
    for (int r = 0; r < 4; ++r) {
      if ((c16 >> 2) == lg && (c16 & 3) == r) {
        bKg[16 * w + c16] = acca[w][r];
        bQg[16 * w + c16] = accq[r];
      }
    }
  }
  __syncthreads();

  // ---- scalar pass: sq/sk + folded scales
  if (tid < C_) {
    const float gv = bG[tid];
    const float gend = bG[C_ - 1];
    const float skv = rsqrtf(bKg[tid] + 1e-6f);
    const float sqv = rsqrtf(bQg[tid] + 1e-6f) * 0.0625f;
    bSk[tid] = skv;
    bSq[tid] = sqv;
    bSc[tid] = __expf(gend - gv) * skv;
    bWl[tid] = bB[tid] * __expf(gv) * skv;
    bQe[tid] = sqv * __expf(gv);
  }
  __syncthreads();

  // ---- masks + scale + scatter: Msc (LDS), AlT -> GLOBAL fp32 [i][t]
  {
    float* gA = wAlT + (size_t)cidx * 4096;
#pragma unroll
    for (int nt = 0; nt < 4; ++nt) {
#pragma unroll
      for (int r = 0; r < 4; ++r) {
        const int t = 16 * w + 4 * lg + r;
        const int i = 16 * nt + c16;
        const float eg = __expf(bG[t] - bG[i]);
        const float ski = bSk[i];
        Msc[t * 72 + i] =
            (ushort)((i <= t) ? rnebf(accm[nt][r] * bSq[t] * ski * eg) : 0u);
        gA[i * 64 + t] =
            (i < t) ? bB[t] * bSk[t] * ski * eg * acca[nt][r] : 0.f;
      }
    }
  }
  // ---- column pass (thread = column d): kT emit + PRE-FS W store (bf16)
  {
    const int d = tid;
    ushort* wb = wWp + (size_t)cidx * C_ * 256;
#pragma unroll
    for (int e = 0; e < 8; ++e) {
      float vj[8];
#pragma unroll
      for (int j = 0; j < 8; ++j) {
        const int t = 8 * e + j;
        const float kv = bf2f(*(const ushort*)((char*)knB + t * 512 +
                                               ((2 * d) ^ ((t & 7) << 4))));
        vj[j] = kv;
        wb[t * 256 + d] = (ushort)rnebf(kv * bWl[t]);
      }
      uint4 o;
      o.x = pkbf(vj[0] * bSc[8 * e + 0], vj[1] * bSc[8 * e + 1]);
      o.y = pkbf(vj[2] * bSc[8 * e + 2], vj[3] * bSc[8 * e + 3]);
      o.z = pkbf(vj[4] * bSc[8 * e + 4], vj[5] * bSc[8 * e + 5]);
      o.w = pkbf(vj[6] * bSc[8 * e + 6], vj[7] * bSc[8 * e + 7]);
      *(uint4*)&wkT[((size_t)cidx * 256 + d) * C_ + 8 * e] = o;
    }
  }
  // ---- Qd emit: Qd = q_raw * sq * exp(G)
#pragma unroll
  for (int rr = 0; rr < 16; ++rr) {
    const int row = rr * 4 + w;
    const float qe = bQe[row];
    const uint2 pq =
        *(const uint2*)((char*)qnB + row * 512 + ((8 * l) ^ ((row & 7) << 4)));
    const float q0 = bf2f(pq.x), q1 = bf2f(pq.x >> 16);
    const float q2 = bf2f(pq.y), q3 = bf2f(pq.y >> 16);
    uint2 oq;
    oq.x = pkbf(q0 * qe, q1 * qe);
    oq.y = pkbf(q2 * qe, q3 * qe);
    *(uint2*)&wQd[(srow0 + (size_t)row * H_) * DK_ + 4 * l] = oq;
  }
  __syncthreads();  // Msc writes visible

  // ---- M store (vectorized from Msc)
  {
    const int row = tid >> 2;
#pragma unroll
    for (int e = 0; e < 2; ++e) {
      const int col = ((tid & 3) * 2 + e) * 8;
      *(uint4*)&wMp[(size_t)cidx * C_ * C_ + row * C_ + col] =
          *(const uint4*)&Msc[row * 72 + col];
    }
  }
  (void)wScl;
}

// ---------------------------------------------------------------------------
// Kernel 3b (parallel, register-heavy phase): forward substitution.
// (R20-proven) LDS 17.7 KB, single-pass dual FS in registers.
// ---------------------------------------------------------------------------
__global__ __launch_bounds__(256) void gdn_prep_fs_kernel(
    const float* __restrict__ v, const float* __restrict__ beta,
    const float* __restrict__ wAlT, ushort* __restrict__ wWp,
    uint2* __restrict__ wUp) {
  __shared__ __attribute__((aligned(16))) float AlT[64 * 68];
  __shared__ float bB[64];

  const int slot = blockIdx.x;
  const int bhx = slot & 15;
  if (bhx >= B_ * H_) return;
  const int nc = slot >> 4;
  const int bh = bhx;
  const int b = bh / H_, h = bh - b * H_;
  const int tid = threadIdx.x;
  const int cidx = bh * NC_ + nc;
  const size_t srow0 = ((size_t)b * T_ + nc * C_) * H_ + h;

  // stage AlT [64][64] global -> [64][68] LDS (coalesced)
  {
    const float* gA = wAlT + (size_t)cidx * 4096;
#pragma unroll
    for (int it = 0; it < 16; ++it) {
      const int idx = it * 256 + tid;
      AlT[(idx >> 6) * 68 + (idx & 63)] = gA[idx];
    }
  }
  if (tid < C_) bB[tid] = beta[srow0 + (size_t)tid * H_];
  __syncthreads();

  // ---- xw init: pre-FS W from wWp (coalesced bf16 column read)
  float xw[64];
  ushort* wb = wWp + (size_t)cidx * C_ * 256;
#pragma unroll
  for (int t = 0; t < C_; ++t) xw[t] = bf2f(wb[t * 256 + tid]);

  // ---- xu init: beta*V, coalesced column read
  float xu[64];
#pragma unroll
  for (int t = 0; t < C_; ++t)
    xu[t] = v[(srow0 + (size_t)t * H_) * DV_ + tid] * bB[t];

  // ---- forward substitution IN REGISTERS (AlT broadcast reads only)
#pragma unroll
  for (int tb = 0; tb < 8; ++tb) {
#pragma unroll
    for (int i = 0; i < 8 * tb; ++i) {
      const float xui = xu[i];
      const float xwi = xw[i];
      float av[8];
      *(float4*)&av[0] = *(float4*)&AlT[i * 68 + 8 * tb];
      *(float4*)&av[4] = *(float4*)&AlT[i * 68 + 8 * tb + 4];
#pragma unroll
      for (int e = 0; e < 8; ++e) {
        xu[8 * tb + e] = fmaf(-av[e], xui, xu[8 * tb + e]);
        xw[8 * tb + e] = fmaf(-av[e], xwi, xw[8 * tb + e]);
      }
    }
#pragma unroll
    for (int e = 1; e < 8; ++e)
#pragma unroll
      for (int m = 0; m < 7; ++m)
        if (m < e) {
          const float am = AlT[(8 * tb + m) * 68 + 8 * tb + e];
          xu[8 * tb + e] = fmaf(-am, xu[8 * tb + m], xu[8 * tb + e]);
          xw[8 * tb + e] = fmaf(-am, xw[8 * tb + m], xw[8 * tb + e]);
        }
  }
  // ---- store W (bf16 row-major, coalesced) and U (C/D-fragment pairs)
  {
#pragma unroll
    for (int row = 0; row < C_; ++row)
      wb[row * 256 + tid] = (ushort)rnebf(xw[row]);
    const int cbw = tid >> 4, c16s = tid & 15;
#pragma unroll
    for (int mt = 0; mt < 4; ++mt) {
#pragma unroll
      for (int lgi = 0; lgi < 4; ++lgi) {
        const int r0 = 16 * mt + 4 * lgi;
        uint2 val;
        val.x = pkbf(xu[r0 + 0], xu[r0 + 1]);
        val.y = pkbf(xu[r0 + 2], xu[r0 + 3]);
        wUp[(((size_t)cidx * 16 + cbw) * 4 + mt) * 64 + (lgi << 4) + c16s] = val;
      }
    }
  }
}

// ---------------------------------------------------------------------------
// Kernel 4 (sequential, MFMA, k-split): grid 256 = cb*16 + bh (XCD = bh%8);
// 2 waves per block: wave kh owns S rows kh*128..+127 for col-block cb.
// ---------------------------------------------------------------------------
__global__ __launch_bounds__(128, 1) void gdn_seq_kernel(
    const ushort* __restrict__ wkT, const ushort* __restrict__ wWp,
    const uint2* __restrict__ wUp, const float* __restrict__ lam,
    uint2* __restrict__ wDP, uint2* __restrict__ wSP) {
  const int bid = blockIdx.x;
  const int cb = bid >> 4, bhx = bid & 15;
  if (bhx >= B_ * H_) return;
  const int bh = bhx;
  const int tid = threadIdx.x;
  const int kh = tid >> 6, l = tid & 63;
  const int lg = l >> 4, c16 = l & 15;
  const int xorv = (c16 & 7) << 4;

  __shared__ ushort sW[2][16384];
  __shared__ ushort sK[2][16384];
  __shared__ uint2 sU[2][256];
  __shared__ f32x4 sX[2][4][64];
  __shared__ float sLam[NC_];

  auto stage = [&](int pp, int cidx2) {
    const char* gw_ = (const char*)(wWp + (size_t)cidx2 * 16384);
#pragma unroll
    for (int j = 0; j < 16; ++j) {
      const int i = kh * 16 + j;
      const int row = 2 * i + (l >> 5);
      const int colb = ((l & 31) * 16) ^ ((row & 7) << 4);
      gload_lds16(gw_ + row * 512 + colb, (char*)&sW[pp][0] + i * 1024);
    }
    const char* gk_ = (const char*)(wkT + (size_t)cidx2 * 16384);
#pragma unroll
    for (int j = 0; j < 16; ++j) {
      const int i = kh * 16 + j;
      const int row = 8 * i + (l >> 3);
      const int colb = ((l & 7) * 16) ^ ((row & 7) << 4);
      gload_lds16(gk_ + row * 128 + colb, (char*)&sK[pp][0] + i * 1024);
    }
    const char* gu_ = (const char*)wUp + ((size_t)cidx2 * 16 + cb) * 2048;
    gload_lds16(gu_ + kh * 1024 + l * 16, (char*)&sU[pp][0] + kh * 1024);
  };

  f32x4 S[8];
#pragma unroll
  for (int m2 = 0; m2 < 8; ++m2) S[m2] = (f32x4){0.f, 0.f, 0.f, 0.f};

  stage(0, bh * NC_ + 0);
  stage(1, bh * NC_ + 1);
  if (tid < NC_) sLam[tid] = lam[bh * NC_ + tid];
  asm volatile("s_waitcnt lgkmcnt(0)" ::: "memory");
  __builtin_amdgcn_sched_barrier(0);
  __builtin_amdgcn_s_barrier();
  __builtin_amdgcn_sched_barrier(0);

  for (int nc = 0; nc < NC_; ++nc) {
    const int pp = nc & 1;
    const int cidx = bh * NC_ + nc;
    if (nc == 0)
      asm volatile("s_waitcnt vmcnt(33)" ::: "memory");
    else if (nc == NC_ - 1)
      asm volatile("s_waitcnt vmcnt(5)" ::: "memory");
    else
      asm volatile("s_waitcnt vmcnt(38)" ::: "memory");
    __builtin_amdgcn_sched_barrier(0);
    __builtin_amdgcn_s_barrier();
    __builtin_amdgcn_sched_barrier(0);

    uint2 P[8];
#pragma unroll
    for (int m2 = 0; m2 < 8; ++m2) {
      P[m2].x = pkbf(S[m2][0], S[m2][1]);
      P[m2].y = pkbf(S[m2][2], S[m2][3]);
    }
    {
      uint4* sp4 = (uint4*)(wSP + (((size_t)cidx * 16 + cb) * 64 + l) * 16 +
                            kh * 8);
#pragma unroll
      for (int i = 0; i < 4; ++i) {
        uint4 o; o.x = P[2 * i].x; o.y = P[2 * i].y;
        o.z = P[2 * i + 1].x; o.w = P[2 * i + 1].y;
        sp4[i] = o;
      }
    }

    f32x4 pe[4], po[4];
#pragma unroll
    for (int mt = 0; mt < 4; ++mt) {
      pe[mt] = (f32x4){0.f, 0.f, 0.f, 0.f};
      po[mt] = (f32x4){0.f, 0.f, 0.f, 0.f};
    }
    const char* sWb = (const char*)&sW[pp][0];
#pragma unroll
    for (int ktl = 0; ktl < 4; ++ktl) {
      const int kt = kh * 4 + ktl;
      const short8 Bf = buildB(P[2 * ktl], P[2 * ktl + 1], lg, c16);
      const int colb = (64 * kt + 16 * lg) ^ xorv;
#pragma unroll
      for (int mt = 0; mt < 4; ++mt) {
        const uint4 aw = *(const uint4*)(sWb + (16 * mt + c16) * 512 + colb);
        if (ktl & 1)
          po[mt] = __builtin_amdgcn_mfma_f32_16x16x32_bf16(u4_to_s8(aw), Bf,
                                                           po[mt], 0, 0, 0);
        else
          pe[mt] = __builtin_amdgcn_mfma_f32_16x16x32_bf16(u4_to_s8(aw), Bf,
                                                           pe[mt], 0, 0, 0);
      }
    }
    f32x4 pl[4];
#pragma unroll
    for (int mt = 0; mt < 4; ++mt) {
      pl[mt] = pe[mt] + po[mt];
      sX[kh][mt][l] = pl[mt];
    }
    asm volatile("s_waitcnt lgkmcnt(0)" ::: "memory");
    __builtin_amdgcn_sched_barrier(0);
    __builtin_amdgcn_s_barrier();
    __builtin_amdgcn_sched_barrier(0);

    uint2 DP[4];
#pragma unroll
    for (int mt = 0; mt < 4; ++mt) {
      const f32x4 pr = sX[kh ^ 1][mt][l];
      const uint2 uu = sU[pp][mt * 64 + l];
      const float d0 = bf2f(uu.x) - (pl[mt][0] + pr[0]);
      const float d1 = bf2f(uu.x >> 16) - (pl[mt][1] + pr[1]);
      const float d2 = bf2f(uu.y) - (pl[mt][2] + pr[2]);
      const float d3 = bf2f(uu.y >> 16) - (pl[mt][3] + pr[3]);
      DP[mt].x = pkbf(d0, d1);
      DP[mt].y = pkbf(d2, d3);
    }
    {
      uint4* dp4 = (uint4*)(wDP + (((size_t)cidx * 16 + cb) * 64 + l) * 4);
      uint4 od;
      if (kh == 0) { od.x = DP[0].x; od.y = DP[0].y; od.z = DP[1].x; od.w = DP[1].y; }
      else         { od.x = DP[2].x; od.y = DP[2].y; od.z = DP[3].x; od.w = DP[3].y; }
      dp4[kh] = od;
    }
    const float lamC = sLam[nc];
#pragma unroll
    for (int m2 = 0; m2 < 8; ++m2) {
      S[m2][0] *= lamC; S[m2][1] *= lamC; S[m2][2] *= lamC; S[m2][3] *= lamC;
    }
    const char* sKb = (const char*)&sK[pp][0];
#pragma unroll
    for (int kt2 = 0; kt2 < 2; ++kt2) {
      const short8 Bd = buildB(DP[2 * kt2], DP[2 * kt2 + 1], lg, c16);
      const int colb = (64 * kt2 + 16 * lg) ^ xorv;
#pragma unroll
      for (int m2 = 0; m2 < 8; ++m2) {
        const int m2g = kh * 8 + m2;
        const uint4 ak = *(const uint4*)(sKb + (16 * m2g + c16) * 128 + colb);
        S[m2] = __builtin_amdgcn_mfma_f32_16x16x32_bf16(u4_to_s8(ak), Bd,
                                                        S[m2], 0, 0, 0);
      }
    }
    __builtin_amdgcn_sched_barrier(0);
    __builtin_amdgcn_s_barrier();
    __builtin_amdgcn_sched_barrier(0);
    if (nc + 2 < NC_) stage(pp, cidx + 2);
    __builtin_amdgcn_sched_barrier(0);
  }
}

// ---------------------------------------------------------------------------
// Kernel 5 (parallel, MFMA, fused epilogue): grid 512 = nc*16 + bh.
// ---------------------------------------------------------------------------
__global__ __launch_bounds__(256) void gdn_ofin_kernel(
    const ushort* __restrict__ wQd, const ushort* __restrict__ wMp,
    const uint2* __restrict__ wDP, const uint2* __restrict__ wSP,
    const float* __restrict__ sgate, const float* __restrict__ norm_w,
    const ushort* __restrict__ owT, float* __restrict__ out) {
  const int slot = blockIdx.x;
  const int bhx = slot & 15;
  if (bhx >= B_ * H_) return;
  const int nc = slot >> 4;
  const int bh = bhx;
  const int cidx = bh * NC_ + nc;
  const int b = bh / H_, h = bh - b * H_;
  const int tid = threadIdx.x;
  const int w = tid >> 6, l = tid & 63;
  const int lg = l >> 4, c16 = l & 15;
  const size_t t0 = (size_t)b * T_ + nc * C_;

  __shared__ ushort onl[64 * 256];
  __shared__ float red[64][4];
  __shared__ float rowf[64];

  f32x4 acc[4][4];
#pragma unroll
  for (int mt = 0; mt < 4; ++mt)
#pragma unroll
    for (int nt = 0; nt < 4; ++nt) acc[mt][nt] = (f32x4){0.f, 0.f, 0.f, 0.f};

#pragma unroll
  for (int nt = 0; nt < 4; ++nt) {
    const int cbwq = 4 * w + nt;
    uint2 SPl[16];
    const uint4* sp4 =
        (const uint4*)(wSP + (((size_t)cidx * 16 + cbwq) * 64 + l) * 16);
#pragma unroll
    for (int i = 0; i < 8; ++i) {
      const uint4 t4 = sp4[i];
      SPl[2 * i].x = t4.x; SPl[2 * i].y = t4.y;
      SPl[2 * i + 1].x = t4.z; SPl[2 * i + 1].y = t4.w;
    }
#pragma unroll
    for (int kt = 0; kt < 8; ++kt) {
      const short8 Bf = buildB(SPl[2 * kt], SPl[2 * kt + 1], lg, c16);
#pragma unroll
      for (int mt = 0; mt < 4; ++mt) {
        const uint4 aq = *(const uint4*)&wQd[((t0 + 16 * mt + c16) * H_ + h) *
                                                 (size_t)DK_ +
                                             32 * kt + 8 * lg];
        acc[mt][nt] = __builtin_amdgcn_mfma_f32_16x16x32_bf16(
            u4_to_s8(aq), Bf, acc[mt][nt], 0, 0, 0);
      }
    }
  }
  const ushort* Mb = wMp + (size_t)cidx * C_ * C_;
#pragma unroll
  for (int nt = 0; nt < 4; ++nt) {
    const int cbwq = 4 * w + nt;
    uint2 DPl[4];
    {
      const uint4* dp4 =
          (const uint4*)(wDP + (((size_t)cidx * 16 + cbwq) * 64 + l) * 4);
      const uint4 a0 = dp4[0], a1 = dp4[1];
      DPl[0].x = a0.x; DPl[0].y = a0.y; DPl[1].x = a0.z; DPl[1].y = a0.w;
      DPl[2].x = a1.x; DPl[2].y = a1.y; DPl[3].x = a1.z; DPl[3].y = a1.w;
    }
#pragma unroll
    for (int kt2 = 0; kt2 < 2; ++kt2) {
      const short8 Bf = buildB(DPl[2 * kt2], DPl[2 * kt2 + 1], lg, c16);
#pragma unroll
      for (int mt = 0; mt < 4; ++mt) {
        const uint4 am =
            *(const uint4*)&Mb[(16 * mt + c16) * C_ + 32 * kt2 + 8 * lg];
        acc[mt][nt] = __builtin_amdgcn_mfma_f32_16x16x32_bf16(
            u4_to_s8(am), Bf, acc[mt][nt], 0, 0, 0);
      }
    }
  }

  float ss[4][4];
#pragma unroll
  for (int mt = 0; mt < 4; ++mt)
#pragma unroll
    for (int r = 0; r < 4; ++r) {
      float s = acc[mt][0][r] * acc[mt][0][r];
      s = fmaf(acc[mt][1][r], acc[mt][1][r], s);
      s = fmaf(acc[mt][2][r], acc[mt][2][r], s);
      s = fmaf(acc[mt][3][r], acc[mt][3][r], s);
      s += __shfl_xor(s, 1);
      s += __shfl_xor(s, 2);
      s += __shfl_xor(s, 4);
      s += __shfl_xor(s, 8);
      ss[mt][r] = s;
    }
  if (c16 == 0) {
#pragma unroll
    for (int mt = 0; mt < 4; ++mt)
#pragma unroll
      for (int r = 0; r < 4; ++r) red[16 * mt + 4 * lg + r][w] = ss[mt][r];
  }
  __syncthreads();
  if (tid < 64) {
    const float ms =
        (red[tid][0] + red[tid][1] + red[tid][2] + red[tid][3]) * (1.f / DV_);
    const float sg = sgate[(t0 + tid) * H_ + h];
    rowf[tid] = rsqrtf(ms + 1e-5f) * sg;
  }
  __syncthreads();

  {
    char* onb = (char*)onl;
#pragma unroll
    for (int mt = 0; mt < 4; ++mt) {
      float rf[4];
#pragma unroll
      for (int r = 0; r < 4; ++r) rf[r] = rowf[16 * mt + 4 * lg + r];
#pragma unroll
      for (int nt = 0; nt < 4; ++nt) {
        const int c = (4 * w + nt) * 16 + c16;
        const float nwv = norm_w[c];
#pragma unroll
        for (int r = 0; r < 4; ++r) {
          const int row = 16 * mt + 4 * lg + r;
          const float v = acc[mt][nt][r] * rf[r] * nwv;
          *(ushort*)(onb + row * 512 + ((2 * c) ^ ((row & 7) << 4))) =
              (ushort)rnebf(v);
        }
      }
    }
  }
  __syncthreads();

  f32x4 acc2[4][4];
#pragma unroll
  for (int mt = 0; mt < 4; ++mt)
#pragma unroll
    for (int nt2 = 0; nt2 < 4; ++nt2)
      acc2[mt][nt2] = (f32x4){0.f, 0.f, 0.f, 0.f};
  {
    const char* onb = (const char*)onl;
#pragma unroll
    for (int kt = 0; kt < 8; ++kt) {
      uint4 af[4];
#pragma unroll
      for (int mt = 0; mt < 4; ++mt)
        af[mt] = *(const uint4*)(onb + (16 * mt + c16) * 512 +
                                 ((64 * kt + 16 * lg) ^ ((c16 & 7) << 4)));
#pragma unroll
      for (int nt2 = 0; nt2 < 4; ++nt2) {
        const uint4 bf = *(const uint4*)&owT[((size_t)h * 256 +
                                              (4 * w + nt2) * 16 + c16) *
                                                 256 +
                                             32 * kt + 8 * lg];
#pragma unroll
        for (int mt = 0; mt < 4; ++mt)
          acc2[mt][nt2] = __builtin_amdgcn_mfma_f32_16x16x32_bf16(
              u4_to_s8(af[mt]), u4_to_s8(bf), acc2[mt][nt2], 0, 0, 0);
      }
    }
  }
#pragma unroll
  for (int mt = 0; mt < 4; ++mt)
#pragma unroll
    for (int nt2 = 0; nt2 < 4; ++nt2)
#pragma unroll
      for (int r = 0; r < 4; ++r)
        out[((t0 + 16 * mt + 4 * lg + r) * H_ + h) * (size_t)DK_ +
            (4 * w + nt2) * 16 + c16] = acc2[mt][nt2][r];
}

// ---------------------------------------------------------------------------
extern "C" void kernel_launch(void* const* d_in, const int* in_sizes, int n_in,
                              void* d_out, int out_size, void* d_ws,
                              size_t ws_size, hipStream_t stream) {
  const float* hab = (const float*)d_in[0];
  const float* hg = (const float*)d_in[1];
  const float* q = (const float*)d_in[2];
  const float* k = (const float*)d_in[3];
  const float* v = (const float*)d_in[4];
  const float* b_w = (const float*)d_in[5];
  const float* a_w = (const float*)d_in[6];
  const float* A_log = (const float*)d_in[7];
  const float* dt_bias = (const float*)d_in[8];
  const float* g_w = (const float*)d_in[9];
  const float* norm_w = (const float*)d_in[10];
  const float* o_w = (const float*)d_in[11];
  float* out = (float*)d_out;

  float* ws = (float*)d_ws;
  const size_t NBT = (size_t)B_ * T_ * H_;  // 24576
  float* w_beta = ws;
  float* w_g = ws + NBT;
  float* w_sg = ws + 2 * NBT;
  float* w_G = ws + 5 * NBT;
  float* w_lam = ws + 7 * NBT;                     // B*H*NC = 384 (pad 1024)
  ushort* w_Qd = (ushort*)(ws + 7 * NBT + 1024);   // 12,582,912 u16
  ushort* w_kT = w_Qd + (size_t)12582912;          // 6,291,456 u16
  ushort* w_W = w_kT + (size_t)6291456;            // 6,291,456 u16
  ushort* w_M = w_W + (size_t)6291456;             // 1,572,864 u16
  uint2* w_U = (uint2*)(w_M + (size_t)1572864);    // 1,572,864 uint2
  uint2* w_DP = w_U + (size_t)1572864;             // 1,572,864 uint2
  uint2* w_SP = w_DP + (size_t)1572864;            // 6,291,456 uint2
  ushort* w_owT = (ushort*)(w_SP + (size_t)6291456);  // 393,216 u16
  float* w_AlT = (float*)(w_owT + (size_t)393216);    // 1,572,864 f32

  hipLaunchKernelGGL(gdn_proj_kernel, dim3(B_ * T_), dim3(256), 0, stream,
                     hab, hg, b_w, a_w, g_w, A_log, dt_bias, w_beta, w_g,
                     w_sg);
  hipLaunchKernelGGL(gdn_cum_kernel, dim3(B_ * H_), dim3(256), 0, stream,
                     w_g, w_G, w_lam);
  hipLaunchKernelGGL(gdn_prep_mfma_kernel, dim3(512 + 24), dim3(256), 0,
                     stream, q, k, w_beta, w_G, w_W, w_M, w_Qd, w_kT, w_AlT,
                     nullptr, o_w, w_owT);
  hipLaunchKernelGGL(gdn_prep_fs_kernel, dim3(512), dim3(256), 0, stream,
                     v, w_beta, w_AlT, w_W, w_U);
  hipLaunchKernelGGL(gdn_seq_kernel, dim3(256), dim3(128), 0, stream,
                     w_kT, w_W, w_U, w_lam, w_DP, w_SP);
  hipLaunchKernelGGL(gdn_ofin_kernel, dim3(512), dim3(256), 0, stream,
                     w_Qd, w_M, w_DP, w_SP, w_sg, norm_w, w_owT, out);
}

// Round 23
// 243.878 us; speedup vs baseline: 1.1007x; 1.0278x over previous
//
#include <hip/hip_runtime.h>
#include <hip/hip_bf16.h>
#include <math.h>

#define B_ 2
#define T_ 2048
#define H_ 6
#define DK_ 256
#define DV_ 256
#define HID_ 2048
#define C_ 64
#define NC_ 32

typedef __attribute__((ext_vector_type(8))) short short8;
typedef __attribute__((ext_vector_type(4))) float f32x4;

__device__ __forceinline__ unsigned rnebf(float f) {
  unsigned u = __float_as_uint(f);
  return (u + 0x7fffu + ((u >> 16) & 1u)) >> 16;
}
__device__ __forceinline__ unsigned pkbf(float lo, float hi) {
  return rnebf(lo) | (rnebf(hi) << 16);
}
__device__ __forceinline__ float bf2f(unsigned u16v) {
  return __uint_as_float((u16v & 0xffffu) << 16);
}
__device__ __forceinline__ short8 u4_to_s8(uint4 u) {
  union { uint4 u; short8 s; } c; c.u = u; return c.s;
}

// async global->LDS 16B per lane; LDS dest wave-uniform base + lane*16
__device__ __forceinline__ void gload_lds16(const void* g, void* l) {
  __builtin_amdgcn_global_load_lds(
      (const __attribute__((address_space(1))) unsigned int*)g,
      (__attribute__((address_space(3))) unsigned int*)l, 16, 0, 0);
}

// Build MFMA B-fragment (16x16x32 bf16) for a k-tile from two C/D-layout
// packed mtiles Pe (even 16 rows) and Po (odd 16 rows).
__device__ __forceinline__ short8 buildB(uint2 Pe, uint2 Po, int lg, int c16) {
  const int src0 = ((2 * (lg & 1)) << 4) | c16;
  const int src1 = src0 + 16;
  int e0 = __shfl((int)Pe.x, src0), o0 = __shfl((int)Po.x, src0);
  int e1 = __shfl((int)Pe.y, src0), o1 = __shfl((int)Po.y, src0);
  int e2 = __shfl((int)Pe.x, src1), o2 = __shfl((int)Po.x, src1);
  int e3 = __shfl((int)Pe.y, src1), o3 = __shfl((int)Po.y, src1);
  const bool lo2 = (lg < 2);
  union { int i[4]; short8 s; } u;
  u.i[0] = lo2 ? e0 : o0;
  u.i[1] = lo2 ? e1 : o1;
  u.i[2] = lo2 ? e2 : o2;
  u.i[3] = lo2 ? e3 : o3;
  return u.s;
}

// ---------------------------------------------------------------------------
// Kernel 1: fused projections. 512 threads; thread t owns weight float4 #t
// of all 18 rows IN REGISTERS (72 VGPR, loaded once); G=8 timesteps/block
// amortize weight traffic 590 MB -> 74 MB L2. Grid 512.
// ---------------------------------------------------------------------------
__global__ __launch_bounds__(512) void gdn_proj_kernel(
    const float* __restrict__ hab, const float* __restrict__ hg,
    const float* __restrict__ b_w, const float* __restrict__ a_w,
    const float* __restrict__ g_w, const float* __restrict__ A_log,
    const float* __restrict__ dt_bias,
    float* __restrict__ beta_o, float* __restrict__ g_o,
    float* __restrict__ sgate_o) {
  const int tid = threadIdx.x;
  const int lane = tid & 63;
  const int wid = tid >> 6;
  const int col = 4 * tid;

  float4 wreg[18];
#pragma unroll
  for (int n = 0; n < 6; ++n) {
    wreg[n] = *(const float4*)(b_w + n * HID_ + col);
    wreg[6 + n] = *(const float4*)(a_w + n * HID_ + col);
    wreg[12 + n] = *(const float4*)(g_w + n * HID_ + col);
  }

  __shared__ float red[18][8];

  for (int g = 0; g < 8; ++g) {
    const int bt = blockIdx.x * 8 + g;
    const float4 x1 = *(const float4*)(hab + (size_t)bt * HID_ + col);
    const float4 x2 = *(const float4*)(hg + (size_t)bt * HID_ + col);

    float part[18];
#pragma unroll
    for (int n = 0; n < 12; ++n) {
      const float4 wv = wreg[n];
      part[n] = x1.x * wv.x + x1.y * wv.y + x1.z * wv.z + x1.w * wv.w;
    }
#pragma unroll
    for (int n = 12; n < 18; ++n) {
      const float4 wv = wreg[n];
      part[n] = x2.x * wv.x + x2.y * wv.y + x2.z * wv.z + x2.w * wv.w;
    }

#pragma unroll
    for (int i = 0; i < 18; ++i) {
      float x = part[i];
      x += __shfl_xor(x, 1);
      x += __shfl_xor(x, 2);
      x += __shfl_xor(x, 4);
      x += __shfl_xor(x, 8);
      x += __shfl_xor(x, 16);
      x += __shfl_xor(x, 32);
      if (lane == 0) red[i][wid] = x;
    }
    __syncthreads();

    if (tid < 18) {
      float s = red[tid][0];
#pragma unroll
      for (int j = 1; j < 8; ++j) s += red[tid][j];
      if (tid < 6) {
        beta_o[(size_t)bt * H_ + tid] = 1.f / (1.f + __expf(-s));
      } else if (tid < 12) {
        const int n = tid - 6;
        const float x = s + dt_bias[n];
        const float sp = (x > 20.f) ? x : log1pf(__expf(x));
        g_o[(size_t)bt * H_ + n] = -__expf(A_log[n]) * sp;
      } else {
        const int n = tid - 12;
        sgate_o[(size_t)bt * H_ + n] = s / (1.f + __expf(-s));
      }
    }
    __syncthreads();
  }
}

// ---------------------------------------------------------------------------
// Kernel 2: per-chunk inclusive cumsum of g; lam = exp(gend)
// ---------------------------------------------------------------------------
__global__ __launch_bounds__(256) void gdn_cum_kernel(
    const float* __restrict__ g, float* __restrict__ Gc,
    float* __restrict__ lam) {
  const int bh = blockIdx.x;
  const int b = bh / H_, h = bh - b * H_;
  const int w = threadIdx.x >> 6, l = threadIdx.x & 63;
  for (int it = 0; it < 8; ++it) {
    const int nc = it * 4 + w;
    const int tg = nc * C_ + l;
    const size_t srow = ((size_t)b * T_ + tg) * H_ + h;
    float val = g[srow];
#pragma unroll
    for (int ofs = 1; ofs < 64; ofs <<= 1) {
      const float o = __shfl_up(val, ofs);
      if (l >= ofs) val += o;
    }
    Gc[(bh * NC_ + nc) * C_ + l] = val;
    if (l == 63) lam[bh * NC_ + nc] = __expf(val);
  }
}

// ---------------------------------------------------------------------------
// Kernel 3a (parallel, LDS-heavy phase): stages RAW q/k bf16; M=q.k^T,
// A=k.k^T, diag -> sq/sk via MFMA; emits Qd, kT, M, PRE-FS W (kn*bWl, bf16)
// and AlT -> GLOBAL (fp32). LDS 75.3 KB -> 2 blocks/CU. (R20-proven)
// ---------------------------------------------------------------------------
__global__ __launch_bounds__(256) void gdn_prep_mfma_kernel(
    const float* __restrict__ q, const float* __restrict__ k,
    const float* __restrict__ beta, const float* __restrict__ Gc,
    ushort* __restrict__ wWp, ushort* __restrict__ wMp,
    ushort* __restrict__ wQd, ushort* __restrict__ wkT,
    float* __restrict__ wAlT, float* __restrict__ wScl,
    const float* __restrict__ o_w, ushort* __restrict__ owT) {
  __shared__ __attribute__((aligned(16))) char smem[77312];

  const int bid = blockIdx.x;
  const int tid = threadIdx.x;

  if (bid >= 512) {
    // ---- o_wT[h][d][v] bf16 path (24 blocks); uses 33.8 KB of smem
    const int b2 = bid - 512;
    const int h2 = b2 >> 2;
    const int db = (b2 & 3) * 64;
    ushort* t = (ushort*)smem;  // [64][264]
#pragma unroll
    for (int it = 0; it < 16; ++it) {
      const int v2 = it * 16 + (tid >> 4);
      const int dl = 4 * (tid & 15);
      const float4 x =
          *(const float4*)&o_w[((size_t)h2 * 256 + v2) * 256 + db + dl];
      t[(dl + 0) * 264 + v2] = (ushort)rnebf(x.x);
      t[(dl + 1) * 264 + v2] = (ushort)rnebf(x.y);
      t[(dl + 2) * 264 + v2] = (ushort)rnebf(x.z);
      t[(dl + 3) * 264 + v2] = (ushort)rnebf(x.w);
    }
    __syncthreads();
#pragma unroll
    for (int it = 0; it < 8; ++it) {
      const int idx = it * 256 + tid;
      const int d = idx >> 5;
      const int vv = (idx & 31) * 8;
      uint4 o;
      o.x = *(uint*)&t[d * 264 + vv + 0]; o.y = *(uint*)&t[d * 264 + vv + 2];
      o.z = *(uint*)&t[d * 264 + vv + 4]; o.w = *(uint*)&t[d * 264 + vv + 6];
      *(uint4*)&owT[((size_t)h2 * 256 + db + d) * 256 + vv] = o;
    }
    return;
  }

  const int bhx = bid & 15;
  if (bhx >= B_ * H_) return;
  const int nc = bid >> 4;
  const int bh = bhx;
  const int b = bh / H_, h = bh - b * H_;
  const int w = tid >> 6, l = tid & 63;
  const int lg = l >> 4, c16 = l & 15;
  const int cidx = bh * NC_ + nc;

  ushort* knB = (ushort*)smem;                   // 32K  (RAW k bf16)
  ushort* qnB = (ushort*)(smem + 32768);         // 32K  (RAW q bf16)
  ushort* Msc = (ushort*)(smem + 65536);         // [64][72] 9216 B
  float* bG = (float*)(smem + 74752);
  float* bB = bG + 64;
  float* bSc = bG + 128;
  float* bWl = bG + 192;
  float* bKg = bG + 256;
  float* bQg = bG + 320;
  float* bSk = bG + 384;
  float* bSq = bG + 448;
  float* bQe = bG + 512;

  const size_t srow0 = ((size_t)b * T_ + nc * C_) * H_ + h;
  if (tid < C_) {
    bG[tid] = Gc[cidx * C_ + tid];
    bB[tid] = beta[srow0 + (size_t)tid * H_];
  }
  __syncthreads();

  // ---- stage RAW q/k (bf16, XOR-swizzled rows of 512 B)
#pragma unroll
  for (int rr = 0; rr < 16; ++rr) {
    const int row = rr * 4 + w;
    const size_t g0 = (srow0 + (size_t)row * H_) * DK_;
    const float4 kv = *(const float4*)(k + g0 + 4 * l);
    const float4 qv = *(const float4*)(q + g0 + 4 * l);
    const int boff = row * 512 + ((8 * l) ^ ((row & 7) << 4));
    uint2 pk_, pq_;
    pk_.x = pkbf(kv.x, kv.y); pk_.y = pkbf(kv.z, kv.w);
    pq_.x = pkbf(qv.x, qv.y); pq_.y = pkbf(qv.z, qv.w);
    *(uint2*)((char*)knB + boff) = pk_;
    *(uint2*)((char*)qnB + boff) = pq_;
  }
  __syncthreads();

  // ---- MFMA: Mraw = q.k^T (32), Araw = k.k^T (32), Qdiag (8)
  f32x4 accm[4], acca[4];
  {
    const int xorv = (c16 & 7) << 4;
    const int rowA = 16 * w + c16;
    uint4 aq[8], ak[8];
#pragma unroll
    for (int kt = 0; kt < 8; ++kt) {
      const int coff = (64 * kt + 16 * lg) ^ xorv;
      aq[kt] = *(const uint4*)((char*)qnB + rowA * 512 + coff);
      ak[kt] = *(const uint4*)((char*)knB + rowA * 512 + coff);
    }
#pragma unroll
    for (int nt = 0; nt < 4; ++nt) {
      accm[nt] = (f32x4){0.f, 0.f, 0.f, 0.f};
      acca[nt] = (f32x4){0.f, 0.f, 0.f, 0.f};
    }
    f32x4 accq = (f32x4){0.f, 0.f, 0.f, 0.f};
#pragma unroll
    for (int nt = 0; nt < 4; ++nt) {
      const int rowB = 16 * nt + c16;
#pragma unroll
      for (int kt = 0; kt < 8; ++kt) {
        const uint4 bk =
            *(const uint4*)((char*)knB + rowB * 512 + ((64 * kt + 16 * lg) ^ xorv));
        const short8 bkf = u4_to_s8(bk);
        accm[nt] = __builtin_amdgcn_mfma_f32_16x16x32_bf16(u4_to_s8(aq[kt]),
                                                           bkf, accm[nt], 0, 0, 0);
        acca[nt] = __builtin_amdgcn_mfma_f32_16x16x32_bf16(u4_to_s8(ak[kt]),
                                                           bkf, acca[nt], 0, 0, 0);
      }
    }
#pragma unroll
    for (int kt = 0; kt < 8; ++kt) {
      const short8 bq = u4_to_s8(aq[kt]);
      accq = __builtin_amdgcn_mfma_f32_16x16x32_bf16(bq, bq, accq, 0, 0, 0);
    }
    // diag extraction: lanes with c16>>2 == lg hold t = 16w + c16 at r=c16&3
#pragma unroll
    for (int r = 0; r < 4; ++r) {
      if ((c16 >> 2) == lg && (c16 & 3) == r) {
        bKg[16 * w + c16] = acca[w][r];
        bQg[16 * w + c16] = accq[r];
      }
    }
  }
  __syncthreads();

  // ---- scalar pass: sq/sk + folded scales
  if (tid < C_) {
    const float gv = bG[tid];
    const float gend = bG[C_ - 1];
    const float skv = rsqrtf(bKg[tid] + 1e-6f);
    const float sqv = rsqrtf(bQg[tid] + 1e-6f) * 0.0625f;
    bSk[tid] = skv;
    bSq[tid] = sqv;
    bSc[tid] = __expf(gend - gv) * skv;
    bWl[tid] = bB[tid] * __expf(gv) * skv;
    bQe[tid] = sqv * __expf(gv);
  }
  __syncthreads();

  // ---- masks + scale + scatter: Msc (LDS), AlT -> GLOBAL fp32 [i][t]
  {
    float* gA = wAlT + (size_t)cidx * 4096;
#pragma unroll
    for (int nt = 0; nt < 4; ++nt) {
#pragma unroll
      for (int r = 0; r < 4; ++r) {
        const int t = 16 * w + 4 * lg + r;
        const int i = 16 * nt + c16;
        const float eg = __expf(bG[t] - bG[i]);
        const float ski = bSk[i];
        Msc[t * 72 + i] =
            (ushort)((i <= t) ? rnebf(accm[nt][r] * bSq[t] * ski * eg) : 0u);
        gA[i * 64 + t] =
            (i < t) ? bB[t] * bSk[t] * ski * eg * acca[nt][r] : 0.f;
      }
    }
  }
  // ---- column pass (thread = column d): kT emit + PRE-FS W store (bf16)
  {
    const int d = tid;
    ushort* wb = wWp + (size_t)cidx * C_ * 256;
#pragma unroll
    for (int e = 0; e < 8; ++e) {
      float vj[8];
#pragma unroll
      for (int j = 0; j < 8; ++j) {
        const int t = 8 * e + j;
        const float kv = bf2f(*(const ushort*)((char*)knB + t * 512 +
                                               ((2 * d) ^ ((t & 7) << 4))));
        vj[j] = kv;
        wb[t * 256 + d] = (ushort)rnebf(kv * bWl[t]);
      }
      uint4 o;
      o.x = pkbf(vj[0] * bSc[8 * e + 0], vj[1] * bSc[8 * e + 1]);
      o.y = pkbf(vj[2] * bSc[8 * e + 2], vj[3] * bSc[8 * e + 3]);
      o.z = pkbf(vj[4] * bSc[8 * e + 4], vj[5] * bSc[8 * e + 5]);
      o.w = pkbf(vj[6] * bSc[8 * e + 6], vj[7] * bSc[8 * e + 7]);
      *(uint4*)&wkT[((size_t)cidx * 256 + d) * C_ + 8 * e] = o;
    }
  }
  // ---- Qd emit: Qd = q_raw * sq * exp(G)
#pragma unroll
  for (int rr = 0; rr < 16; ++rr) {
    const int row = rr * 4 + w;
    const float qe = bQe[row];
    const uint2 pq =
        *(const uint2*)((char*)qnB + row * 512 + ((8 * l) ^ ((row & 7) << 4)));
    const float q0 = bf2f(pq.x), q1 = bf2f(pq.x >> 16);
    const float q2 = bf2f(pq.y), q3 = bf2f(pq.y >> 16);
    uint2 oq;
    oq.x = pkbf(q0 * qe, q1 * qe);
    oq.y = pkbf(q2 * qe, q3 * qe);
    *(uint2*)&wQd[(srow0 + (size_t)row * H_) * DK_ + 4 * l] = oq;
  }
  __syncthreads();  // Msc writes visible

  // ---- M store (vectorized from Msc)
  {
    const int row = tid >> 2;
#pragma unroll
    for (int e = 0; e < 2; ++e) {
      const int col = ((tid & 3) * 2 + e) * 8;
      *(uint4*)&wMp[(size_t)cidx * C_ * C_ + row * C_ + col] =
          *(const uint4*)&Msc[row * 72 + col];
    }
  }
  (void)wScl;
}

// ---------------------------------------------------------------------------
// Kernel 3b (parallel, register-heavy phase): forward substitution.
// (R20-proven) LDS 17.7 KB, single-pass dual FS in registers.
// ---------------------------------------------------------------------------
__global__ __launch_bounds__(256) void gdn_prep_fs_kernel(
    const float* __restrict__ v, const float* __restrict__ beta,
    const float* __restrict__ wAlT, ushort* __restrict__ wWp,
    uint2* __restrict__ wUp) {
  __shared__ __attribute__((aligned(16))) float AlT[64 * 68];
  __shared__ float bB[64];

  const int slot = blockIdx.x;
  const int bhx = slot & 15;
  if (bhx >= B_ * H_) return;
  const int nc = slot >> 4;
  const int bh = bhx;
  const int b = bh / H_, h = bh - b * H_;
  const int tid = threadIdx.x;
  const int cidx = bh * NC_ + nc;
  const size_t srow0 = ((size_t)b * T_ + nc * C_) * H_ + h;

  // stage AlT [64][64] global -> [64][68] LDS (coalesced)
  {
    const float* gA = wAlT + (size_t)cidx * 4096;
#pragma unroll
    for (int it = 0; it < 16; ++it) {
      const int idx = it * 256 + tid;
      AlT[(idx >> 6) * 68 + (idx & 63)] = gA[idx];
    }
  }
  if (tid < C_) bB[tid] = beta[srow0 + (size_t)tid * H_];
  __syncthreads();

  // ---- xw init: pre-FS W from wWp (coalesced bf16 column read)
  float xw[64];
  ushort* wb = wWp + (size_t)cidx * C_ * 256;
#pragma unroll
  for (int t = 0; t < C_; ++t) xw[t] = bf2f(wb[t * 256 + tid]);

  // ---- xu init: beta*V, coalesced column read
  float xu[64];
#pragma unroll
  for (int t = 0; t < C_; ++t)
    xu[t] = v[(srow0 + (size_t)t * H_) * DV_ + tid] * bB[t];

  // ---- forward substitution IN REGISTERS (AlT broadcast reads only)
#pragma unroll
  for (int tb = 0; tb < 8; ++tb) {
#pragma unroll
    for (int i = 0; i < 8 * tb; ++i) {
      const float xui = xu[i];
      const float xwi = xw[i];
      float av[8];
      *(float4*)&av[0] = *(float4*)&AlT[i * 68 + 8 * tb];
      *(float4*)&av[4] = *(float4*)&AlT[i * 68 + 8 * tb + 4];
#pragma unroll
      for (int e = 0; e < 8; ++e) {
        xu[8 * tb + e] = fmaf(-av[e], xui, xu[8 * tb + e]);
        xw[8 * tb + e] = fmaf(-av[e], xwi, xw[8 * tb + e]);
      }
    }
#pragma unroll
    for (int e = 1; e < 8; ++e)
#pragma unroll
      for (int m = 0; m < 7; ++m)
        if (m < e) {
          const float am = AlT[(8 * tb + m) * 68 + 8 * tb + e];
          xu[8 * tb + e] = fmaf(-am, xu[8 * tb + m], xu[8 * tb + e]);
          xw[8 * tb + e] = fmaf(-am, xw[8 * tb + m], xw[8 * tb + e]);
        }
  }
  // ---- store W (bf16 row-major, coalesced) and U (C/D-fragment pairs)
  {
#pragma unroll
    for (int row = 0; row < C_; ++row)
      wb[row * 256 + tid] = (ushort)rnebf(xw[row]);
    const int cbw = tid >> 4, c16s = tid & 15;
#pragma unroll
    for (int mt = 0; mt < 4; ++mt) {
#pragma unroll
      for (int lgi = 0; lgi < 4; ++lgi) {
        const int r0 = 16 * mt + 4 * lgi;
        uint2 val;
        val.x = pkbf(xu[r0 + 0], xu[r0 + 1]);
        val.y = pkbf(xu[r0 + 2], xu[r0 + 3]);
        wUp[(((size_t)cidx * 16 + cbw) * 4 + mt) * 64 + (lgi << 4) + c16s] = val;
      }
    }
  }
}

// ---------------------------------------------------------------------------
// Kernel 4 (sequential, MFMA, k-split): grid 256 = cb*16 + bh (XCD = bh%8);
// 2 waves per block: wave kh owns S rows kh*128..+127 for col-block cb.
// ---------------------------------------------------------------------------
__global__ __launch_bounds__(128, 1) void gdn_seq_kernel(
    const ushort* __restrict__ wkT, const ushort* __restrict__ wWp,
    const uint2* __restrict__ wUp, const float* __restrict__ lam,
    uint2* __restrict__ wDP, uint2* __restrict__ wSP) {
  const int bid = blockIdx.x;
  const int cb = bid >> 4, bhx = bid & 15;
  if (bhx >= B_ * H_) return;
  const int bh = bhx;
  const int tid = threadIdx.x;
  const int kh = tid >> 6, l = tid & 63;
  const int lg = l >> 4, c16 = l & 15;
  const int xorv = (c16 & 7) << 4;

  __shared__ ushort sW[2][16384];
  __shared__ ushort sK[2][16384];
  __shared__ uint2 sU[2][256];
  __shared__ f32x4 sX[2][4][64];
  __shared__ float sLam[NC_];

  auto stage = [&](int pp, int cidx2) {
    const char* gw_ = (const char*)(wWp + (size_t)cidx2 * 16384);
#pragma unroll
    for (int j = 0; j < 16; ++j) {
      const int i = kh * 16 + j;
      const int row = 2 * i + (l >> 5);
      const int colb = ((l & 31) * 16) ^ ((row & 7) << 4);
      gload_lds16(gw_ + row * 512 + colb, (char*)&sW[pp][0] + i * 1024);
    }
    const char* gk_ = (const char*)(wkT + (size_t)cidx2 * 16384);
#pragma unroll
    for (int j = 0; j < 16; ++j) {
      const int i = kh * 16 + j;
      const int row = 8 * i + (l >> 3);
      const int colb = ((l & 7) * 16) ^ ((row & 7) << 4);
      gload_lds16(gk_ + row * 128 + colb, (char*)&sK[pp][0] + i * 1024);
    }
    const char* gu_ = (const char*)wUp + ((size_t)cidx2 * 16 + cb) * 2048;
    gload_lds16(gu_ + kh * 1024 + l * 16, (char*)&sU[pp][0] + kh * 1024);
  };

  f32x4 S[8];
#pragma unroll
  for (int m2 = 0; m2 < 8; ++m2) S[m2] = (f32x4){0.f, 0.f, 0.f, 0.f};

  stage(0, bh * NC_ + 0);
  stage(1, bh * NC_ + 1);
  if (tid < NC_) sLam[tid] = lam[bh * NC_ + tid];
  asm volatile("s_waitcnt lgkmcnt(0)" ::: "memory");
  __builtin_amdgcn_sched_barrier(0);
  __builtin_amdgcn_s_barrier();
  __builtin_amdgcn_sched_barrier(0);

  for (int nc = 0; nc < NC_; ++nc) {
    const int pp = nc & 1;
    const int cidx = bh * NC_ + nc;
    if (nc == 0)
      asm volatile("s_waitcnt vmcnt(33)" ::: "memory");
    else if (nc == NC_ - 1)
      asm volatile("s_waitcnt vmcnt(5)" ::: "memory");
    else
      asm volatile("s_waitcnt vmcnt(38)" ::: "memory");
    __builtin_amdgcn_sched_barrier(0);
    __builtin_amdgcn_s_barrier();
    __builtin_amdgcn_sched_barrier(0);

    uint2 P[8];
#pragma unroll
    for (int m2 = 0; m2 < 8; ++m2) {
      P[m2].x = pkbf(S[m2][0], S[m2][1]);
      P[m2].y = pkbf(S[m2][2], S[m2][3]);
    }
    {
      uint4* sp4 = (uint4*)(wSP + (((size_t)cidx * 16 + cb) * 64 + l) * 16 +
                            kh * 8);
#pragma unroll
      for (int i = 0; i < 4; ++i) {
        uint4 o; o.x = P[2 * i].x; o.y = P[2 * i].y;
        o.z = P[2 * i + 1].x; o.w = P[2 * i + 1].y;
        sp4[i] = o;
      }
    }

    f32x4 pe[4], po[4];
#pragma unroll
    for (int mt = 0; mt < 4; ++mt) {
      pe[mt] = (f32x4){0.f, 0.f, 0.f, 0.f};
      po[mt] = (f32x4){0.f, 0.f, 0.f, 0.f};
    }
    const char* sWb = (const char*)&sW[pp][0];
#pragma unroll
    for (int ktl = 0; ktl < 4; ++ktl) {
      const int kt = kh * 4 + ktl;
      const short8 Bf = buildB(P[2 * ktl], P[2 * ktl + 1], lg, c16);
      const int colb = (64 * kt + 16 * lg) ^ xorv;
#pragma unroll
      for (int mt = 0; mt < 4; ++mt) {
        const uint4 aw = *(const uint4*)(sWb + (16 * mt + c16) * 512 + colb);
        if (ktl & 1)
          po[mt] = __builtin_amdgcn_mfma_f32_16x16x32_bf16(u4_to_s8(aw), Bf,
                                                           po[mt], 0, 0, 0);
        else
          pe[mt] = __builtin_amdgcn_mfma_f32_16x16x32_bf16(u4_to_s8(aw), Bf,
                                                           pe[mt], 0, 0, 0);
      }
    }
    f32x4 pl[4];
#pragma unroll
    for (int mt = 0; mt < 4; ++mt) {
      pl[mt] = pe[mt] + po[mt];
      sX[kh][mt][l] = pl[mt];
    }
    asm volatile("s_waitcnt lgkmcnt(0)" ::: "memory");
    __builtin_amdgcn_sched_barrier(0);
    __builtin_amdgcn_s_barrier();
    __builtin_amdgcn_sched_barrier(0);

    uint2 DP[4];
#pragma unroll
    for (int mt = 0; mt < 4; ++mt) {
      const f32x4 pr = sX[kh ^ 1][mt][l];
      const uint2 uu = sU[pp][mt * 64 + l];
      const float d0 = bf2f(uu.x) - (pl[mt][0] + pr[0]);
      const float d1 = bf2f(uu.x >> 16) - (pl[mt][1] + pr[1]);
      const float d2 = bf2f(uu.y) - (pl[mt][2] + pr[2]);
      const float d3 = bf2f(uu.y >> 16) - (pl[mt][3] + pr[3]);
      DP[mt].x = pkbf(d0, d1);
      DP[mt].y = pkbf(d2, d3);
    }
    {
      uint4* dp4 = (uint4*)(wDP + (((size_t)cidx * 16 + cb) * 64 + l) * 4);
      uint4 od;
      if (kh == 0) { od.x = DP[0].x; od.y = DP[0].y; od.z = DP[1].x; od.w = DP[1].y; }
      else         { od.x = DP[2].x; od.y = DP[2].y; od.z = DP[3].x; od.w = DP[3].y; }
      dp4[kh] = od;
    }
    const float lamC = sLam[nc];
#pragma unroll
    for (int m2 = 0; m2 < 8; ++m2) {
      S[m2][0] *= lamC; S[m2][1] *= lamC; S[m2][2] *= lamC; S[m2][3] *= lamC;
    }
    const char* sKb = (const char*)&sK[pp][0];
#pragma unroll
    for (int kt2 = 0; kt2 < 2; ++kt2) {
      const short8 Bd = buildB(DP[2 * kt2], DP[2 * kt2 + 1], lg, c16);
      const int colb = (64 * kt2 + 16 * lg) ^ xorv;
#pragma unroll
      for (int m2 = 0; m2 < 8; ++m2) {
        const int m2g = kh * 8 + m2;
        const uint4 ak = *(const uint4*)(sKb + (16 * m2g + c16) * 128 + colb);
        S[m2] = __builtin_amdgcn_mfma_f32_16x16x32_bf16(u4_to_s8(ak), Bd,
                                                        S[m2], 0, 0, 0);
      }
    }
    __builtin_amdgcn_sched_barrier(0);
    __builtin_amdgcn_s_barrier();
    __builtin_amdgcn_sched_barrier(0);
    if (nc + 2 < NC_) stage(pp, cidx + 2);
    __builtin_amdgcn_sched_barrier(0);
  }
}

// ---------------------------------------------------------------------------
// Kernel 5 (parallel, MFMA, fused epilogue): grid 512 = nc*16 + bh.
// ---------------------------------------------------------------------------
__global__ __launch_bounds__(256) void gdn_ofin_kernel(
    const ushort* __restrict__ wQd, const ushort* __restrict__ wMp,
    const uint2* __restrict__ wDP, const uint2* __restrict__ wSP,
    const float* __restrict__ sgate, const float* __restrict__ norm_w,
    const ushort* __restrict__ owT, float* __restrict__ out) {
  const int slot = blockIdx.x;
  const int bhx = slot & 15;
  if (bhx >= B_ * H_) return;
  const int nc = slot >> 4;
  const int bh = bhx;
  const int cidx = bh * NC_ + nc;
  const int b = bh / H_, h = bh - b * H_;
  const int tid = threadIdx.x;
  const int w = tid >> 6, l = tid & 63;
  const int lg = l >> 4, c16 = l & 15;
  const size_t t0 = (size_t)b * T_ + nc * C_;

  __shared__ ushort onl[64 * 256];
  __shared__ float red[64][4];
  __shared__ float rowf[64];

  f32x4 acc[4][4];
#pragma unroll
  for (int mt = 0; mt < 4; ++mt)
#pragma unroll
    for (int nt = 0; nt < 4; ++nt) acc[mt][nt] = (f32x4){0.f, 0.f, 0.f, 0.f};

#pragma unroll
  for (int nt = 0; nt < 4; ++nt) {
    const int cbwq = 4 * w + nt;
    uint2 SPl[16];
    const uint4* sp4 =
        (const uint4*)(wSP + (((size_t)cidx * 16 + cbwq) * 64 + l) * 16);
#pragma unroll
    for (int i = 0; i < 8; ++i) {
      const uint4 t4 = sp4[i];
      SPl[2 * i].x = t4.x; SPl[2 * i].y = t4.y;
      SPl[2 * i + 1].x = t4.z; SPl[2 * i + 1].y = t4.w;
    }
#pragma unroll
    for (int kt = 0; kt < 8; ++kt) {
      const short8 Bf = buildB(SPl[2 * kt], SPl[2 * kt + 1], lg, c16);
#pragma unroll
      for (int mt = 0; mt < 4; ++mt) {
        const uint4 aq = *(const uint4*)&wQd[((t0 + 16 * mt + c16) * H_ + h) *
                                                 (size_t)DK_ +
                                             32 * kt + 8 * lg];
        acc[mt][nt] = __builtin_amdgcn_mfma_f32_16x16x32_bf16(
            u4_to_s8(aq), Bf, acc[mt][nt], 0, 0, 0);
      }
    }
  }
  const ushort* Mb = wMp + (size_t)cidx * C_ * C_;
#pragma unroll
  for (int nt = 0; nt < 4; ++nt) {
    const int cbwq = 4 * w + nt;
    uint2 DPl[4];
    {
      const uint4* dp4 =
          (const uint4*)(wDP + (((size_t)cidx * 16 + cbwq) * 64 + l) * 4);
      const uint4 a0 = dp4[0], a1 = dp4[1];
      DPl[0].x = a0.x; DPl[0].y = a0.y; DPl[1].x = a0.z; DPl[1].y = a0.w;
      DPl[2].x = a1.x; DPl[2].y = a1.y; DPl[3].x = a1.z; DPl[3].y = a1.w;
    }
#pragma unroll
    for (int kt2 = 0; kt2 < 2; ++kt2) {
      const short8 Bf = buildB(DPl[2 * kt2], DPl[2 * kt2 + 1], lg, c16);
#pragma unroll
      for (int mt = 0; mt < 4; ++mt) {
        const uint4 am =
            *(const uint4*)&Mb[(16 * mt + c16) * C_ + 32 * kt2 + 8 * lg];
        acc[mt][nt] = __builtin_amdgcn_mfma_f32_16x16x32_bf16(
            u4_to_s8(am), Bf, acc[mt][nt], 0, 0, 0);
      }
    }
  }

  float ss[4][4];
#pragma unroll
  for (int mt = 0; mt < 4; ++mt)
#pragma unroll
    for (int r = 0; r < 4; ++r) {
      float s = acc[mt][0][r] * acc[mt][0][r];
      s = fmaf(acc[mt][1][r], acc[mt][1][r], s);
      s = fmaf(acc[mt][2][r], acc[mt][2][r], s);
      s = fmaf(acc[mt][3][r], acc[mt][3][r], s);
      s += __shfl_xor(s, 1);
      s += __shfl_xor(s, 2);
      s += __shfl_xor(s, 4);
      s += __shfl_xor(s, 8);
      ss[mt][r] = s;
    }
  if (c16 == 0) {
#pragma unroll
    for (int mt = 0; mt < 4; ++mt)
#pragma unroll
      for (int r = 0; r < 4; ++r) red[16 * mt + 4 * lg + r][w] = ss[mt][r];
  }
  __syncthreads();
  if (tid < 64) {
    const float ms =
        (red[tid][0] + red[tid][1] + red[tid][2] + red[tid][3]) * (1.f / DV_);
    const float sg = sgate[(t0 + tid) * H_ + h];
    rowf[tid] = rsqrtf(ms + 1e-5f) * sg;
  }
  __syncthreads();

  {
    char* onb = (char*)onl;
#pragma unroll
    for (int mt = 0; mt < 4; ++mt) {
      float rf[4];
#pragma unroll
      for (int r = 0; r < 4; ++r) rf[r] = rowf[16 * mt + 4 * lg + r];
#pragma unroll
      for (int nt = 0; nt < 4; ++nt) {
        const int c = (4 * w + nt) * 16 + c16;
        const float nwv = norm_w[c];
#pragma unroll
        for (int r = 0; r < 4; ++r) {
          const int row = 16 * mt + 4 * lg + r;
          const float v = acc[mt][nt][r] * rf[r] * nwv;
          *(ushort*)(onb + row * 512 + ((2 * c) ^ ((row & 7) << 4))) =
              (ushort)rnebf(v);
        }
      }
    }
  }
  __syncthreads();

  f32x4 acc2[4][4];
#pragma unroll
  for (int mt = 0; mt < 4; ++mt)
#pragma unroll
    for (int nt2 = 0; nt2 < 4; ++nt2)
      acc2[mt][nt2] = (f32x4){0.f, 0.f, 0.f, 0.f};
  {
    const char* onb = (const char*)onl;
#pragma unroll
    for (int kt = 0; kt < 8; ++kt) {
      uint4 af[4];
#pragma unroll
      for (int mt = 0; mt < 4; ++mt)
        af[mt] = *(const uint4*)(onb + (16 * mt + c16) * 512 +
                                 ((64 * kt + 16 * lg) ^ ((c16 & 7) << 4)));
#pragma unroll
      for (int nt2 = 0; nt2 < 4; ++nt2) {
        const uint4 bf = *(const uint4*)&owT[((size_t)h * 256 +
                                              (4 * w + nt2) * 16 + c16) *
                                                 256 +
                                             32 * kt + 8 * lg];
#pragma unroll
        for (int mt = 0; mt < 4; ++mt)
          acc2[mt][nt2] = __builtin_amdgcn_mfma_f32_16x16x32_bf16(
              u4_to_s8(af[mt]), u4_to_s8(bf), acc2[mt][nt2], 0, 0, 0);
      }
    }
  }
#pragma unroll
  for (int mt = 0; mt < 4; ++mt)
#pragma unroll
    for (int nt2 = 0; nt2 < 4; ++nt2)
#pragma unroll
      for (int r = 0; r < 4; ++r)
        out[((t0 + 16 * mt + 4 * lg + r) * H_ + h) * (size_t)DK_ +
            (4 * w + nt2) * 16 + c16] = acc2[mt][nt2][r];
}

// ---------------------------------------------------------------------------
extern "C" void kernel_launch(void* const* d_in, const int* in_sizes, int n_in,
                              void* d_out, int out_size, void* d_ws,
                              size_t ws_size, hipStream_t stream) {
  const float* hab = (const float*)d_in[0];
  const float* hg = (const float*)d_in[1];
  const float* q = (const float*)d_in[2];
  const float* k = (const float*)d_in[3];
  const float* v = (const float*)d_in[4];
  const float* b_w = (const float*)d_in[5];
  const float* a_w = (const float*)d_in[6];
  const float* A_log = (const float*)d_in[7];
  const float* dt_bias = (const float*)d_in[8];
  const float* g_w = (const float*)d_in[9];
  const float* norm_w = (const float*)d_in[10];
  const float* o_w = (const float*)d_in[11];
  float* out = (float*)d_out;

  float* ws = (float*)d_ws;
  const size_t NBT = (size_t)B_ * T_ * H_;  // 24576
  float* w_beta = ws;
  float* w_g = ws + NBT;
  float* w_sg = ws + 2 * NBT;
  float* w_G = ws + 5 * NBT;
  float* w_lam = ws + 7 * NBT;                     // B*H*NC = 384 (pad 1024)
  ushort* w_Qd = (ushort*)(ws + 7 * NBT + 1024);   // 12,582,912 u16
  ushort* w_kT = w_Qd + (size_t)12582912;          // 6,291,456 u16
  ushort* w_W = w_kT + (size_t)6291456;            // 6,291,456 u16
  ushort* w_M = w_W + (size_t)6291456;             // 1,572,864 u16
  uint2* w_U = (uint2*)(w_M + (size_t)1572864);    // 1,572,864 uint2
  uint2* w_DP = w_U + (size_t)1572864;             // 1,572,864 uint2
  uint2* w_SP = w_DP + (size_t)1572864;            // 6,291,456 uint2
  ushort* w_owT = (ushort*)(w_SP + (size_t)6291456);  // 393,216 u16
  float* w_AlT = (float*)(w_owT + (size_t)393216);    // 1,572,864 f32

  hipLaunchKernelGGL(gdn_proj_kernel, dim3(512), dim3(512), 0, stream,
                     hab, hg, b_w, a_w, g_w, A_log, dt_bias, w_beta, w_g,
                     w_sg);
  hipLaunchKernelGGL(gdn_cum_kernel, dim3(B_ * H_), dim3(256), 0, stream,
                     w_g, w_G, w_lam);
  hipLaunchKernelGGL(gdn_prep_mfma_kernel, dim3(512 + 24), dim3(256), 0,
                     stream, q, k, w_beta, w_G, w_W, w_M, w_Qd, w_kT, w_AlT,
                     nullptr, o_w, w_owT);
  hipLaunchKernelGGL(gdn_prep_fs_kernel, dim3(512), dim3(256), 0, stream,
                     v, w_beta, w_AlT, w_W, w_U);
  hipLaunchKernelGGL(gdn_seq_kernel, dim3(256), dim3(128), 0, stream,
                     w_kT, w_W, w_U, w_lam, w_DP, w_SP);
  hipLaunchKernelGGL(gdn_ofin_kernel, dim3(512), dim3(256), 0, stream,
                     w_Qd, w_M, w_DP, w_SP, w_sg, norm_w, w_owT, out);
}

// Round 24
// 238.646 us; speedup vs baseline: 1.1248x; 1.0219x over previous
//
#include <hip/hip_runtime.h>
#include <hip/hip_bf16.h>
#include <math.h>

#define B_ 2
#define T_ 2048
#define H_ 6
#define DK_ 256
#define DV_ 256
#define HID_ 2048
#define C_ 64
#define NC_ 32

typedef __attribute__((ext_vector_type(8))) short short8;
typedef __attribute__((ext_vector_type(4))) float f32x4;

__device__ __forceinline__ unsigned rnebf(float f) {
  unsigned u = __float_as_uint(f);
  return (u + 0x7fffu + ((u >> 16) & 1u)) >> 16;
}
__device__ __forceinline__ unsigned pkbf(float lo, float hi) {
  return rnebf(lo) | (rnebf(hi) << 16);
}
__device__ __forceinline__ float bf2f(unsigned u16v) {
  return __uint_as_float((u16v & 0xffffu) << 16);
}
__device__ __forceinline__ short8 u4_to_s8(uint4 u) {
  union { uint4 u; short8 s; } c; c.u = u; return c.s;
}

// async global->LDS 16B per lane; LDS dest wave-uniform base + lane*16
__device__ __forceinline__ void gload_lds16(const void* g, void* l) {
  __builtin_amdgcn_global_load_lds(
      (const __attribute__((address_space(1))) unsigned int*)g,
      (__attribute__((address_space(3))) unsigned int*)l, 16, 0, 0);
}

// Build MFMA B-fragment (16x16x32 bf16) for a k-tile from two C/D-layout
// packed mtiles Pe (even 16 rows) and Po (odd 16 rows).
__device__ __forceinline__ short8 buildB(uint2 Pe, uint2 Po, int lg, int c16) {
  const int src0 = ((2 * (lg & 1)) << 4) | c16;
  const int src1 = src0 + 16;
  int e0 = __shfl((int)Pe.x, src0), o0 = __shfl((int)Po.x, src0);
  int e1 = __shfl((int)Pe.y, src0), o1 = __shfl((int)Po.y, src0);
  int e2 = __shfl((int)Pe.x, src1), o2 = __shfl((int)Po.x, src1);
  int e3 = __shfl((int)Pe.y, src1), o3 = __shfl((int)Po.y, src1);
  const bool lo2 = (lg < 2);
  union { int i[4]; short8 s; } u;
  u.i[0] = lo2 ? e0 : o0;
  u.i[1] = lo2 ? e1 : o1;
  u.i[2] = lo2 ? e2 : o2;
  u.i[3] = lo2 ? e3 : o3;
  return u.s;
}

// ---------------------------------------------------------------------------
// Kernel 1: fused projections. 256 threads; thread t owns 8 weight floats of
// all 18 rows IN REGISTERS (144 VGPR). Per timestep only 4 waves x 108
// shfl_xor hit the DS pipe (half of the 512-thread variant). G=8/block.
// ---------------------------------------------------------------------------
__global__ __launch_bounds__(256) void gdn_proj_kernel(
    const float* __restrict__ hab, const float* __restrict__ hg,
    const float* __restrict__ b_w, const float* __restrict__ a_w,
    const float* __restrict__ g_w, const float* __restrict__ A_log,
    const float* __restrict__ dt_bias,
    float* __restrict__ beta_o, float* __restrict__ g_o,
    float* __restrict__ sgate_o) {
  const int tid = threadIdx.x;
  const int lane = tid & 63;
  const int wid = tid >> 6;  // 0..3
  const int col = 8 * tid;   // 256*8 = 2048

  float4 wa[18], wb[18];
#pragma unroll
  for (int n = 0; n < 6; ++n) {
    wa[n] = *(const float4*)(b_w + n * HID_ + col);
    wb[n] = *(const float4*)(b_w + n * HID_ + col + 4);
    wa[6 + n] = *(const float4*)(a_w + n * HID_ + col);
    wb[6 + n] = *(const float4*)(a_w + n * HID_ + col + 4);
    wa[12 + n] = *(const float4*)(g_w + n * HID_ + col);
    wb[12 + n] = *(const float4*)(g_w + n * HID_ + col + 4);
  }

  __shared__ float red[18][4];

  for (int g = 0; g < 8; ++g) {
    const int bt = blockIdx.x * 8 + g;
    const float4 x1a = *(const float4*)(hab + (size_t)bt * HID_ + col);
    const float4 x1b = *(const float4*)(hab + (size_t)bt * HID_ + col + 4);
    const float4 x2a = *(const float4*)(hg + (size_t)bt * HID_ + col);
    const float4 x2b = *(const float4*)(hg + (size_t)bt * HID_ + col + 4);

    float part[18];
#pragma unroll
    for (int n = 0; n < 12; ++n) {
      const float4 va = wa[n], vb = wb[n];
      part[n] = x1a.x * va.x + x1a.y * va.y + x1a.z * va.z + x1a.w * va.w +
                x1b.x * vb.x + x1b.y * vb.y + x1b.z * vb.z + x1b.w * vb.w;
    }
#pragma unroll
    for (int n = 12; n < 18; ++n) {
      const float4 va = wa[n], vb = wb[n];
      part[n] = x2a.x * va.x + x2a.y * va.y + x2a.z * va.z + x2a.w * va.w +
                x2b.x * vb.x + x2b.y * vb.y + x2b.z * vb.z + x2b.w * vb.w;
    }

#pragma unroll
    for (int i = 0; i < 18; ++i) {
      float x = part[i];
      x += __shfl_xor(x, 1);
      x += __shfl_xor(x, 2);
      x += __shfl_xor(x, 4);
      x += __shfl_xor(x, 8);
      x += __shfl_xor(x, 16);
      x += __shfl_xor(x, 32);
      if (lane == 0) red[i][wid] = x;
    }
    __syncthreads();

    if (tid < 18) {
      const float s = red[tid][0] + red[tid][1] + red[tid][2] + red[tid][3];
      if (tid < 6) {
        beta_o[(size_t)bt * H_ + tid] = 1.f / (1.f + __expf(-s));
      } else if (tid < 12) {
        const int n = tid - 6;
        const float x = s + dt_bias[n];
        const float sp = (x > 20.f) ? x : log1pf(__expf(x));
        g_o[(size_t)bt * H_ + n] = -__expf(A_log[n]) * sp;
      } else {
        const int n = tid - 12;
        sgate_o[(size_t)bt * H_ + n] = s / (1.f + __expf(-s));
      }
    }
    __syncthreads();
  }
}

// ---------------------------------------------------------------------------
// Kernel 2: per-chunk inclusive cumsum of g; lam = exp(gend)
// ---------------------------------------------------------------------------
__global__ __launch_bounds__(256) void gdn_cum_kernel(
    const float* __restrict__ g, float* __restrict__ Gc,
    float* __restrict__ lam) {
  const int bh = blockIdx.x;
  const int b = bh / H_, h = bh - b * H_;
  const int w = threadIdx.x >> 6, l = threadIdx.x & 63;
  for (int it = 0; it < 8; ++it) {
    const int nc = it * 4 + w;
    const int tg = nc * C_ + l;
    const size_t srow = ((size_t)b * T_ + tg) * H_ + h;
    float val = g[srow];
#pragma unroll
    for (int ofs = 1; ofs < 64; ofs <<= 1) {
      const float o = __shfl_up(val, ofs);
      if (l >= ofs) val += o;
    }
    Gc[(bh * NC_ + nc) * C_ + l] = val;
    if (l == 63) lam[bh * NC_ + nc] = __expf(val);
  }
}

// ---------------------------------------------------------------------------
// Kernel 3a (parallel, LDS-heavy phase): stages RAW q/k bf16; M=q.k^T,
// A=k.k^T, diag -> sq/sk via MFMA; emits Qd, kT, M, PRE-FS W (kn*bWl, bf16)
// and AlT -> GLOBAL (fp32). LDS 75.3 KB -> 2 blocks/CU. (R20-proven)
// ---------------------------------------------------------------------------
__global__ __launch_bounds__(256) void gdn_prep_mfma_kernel(
    const float* __restrict__ q, const float* __restrict__ k,
    const float* __restrict__ beta, const float* __restrict__ Gc,
    ushort* __restrict__ wWp, ushort* __restrict__ wMp,
    ushort* __restrict__ wQd, ushort* __restrict__ wkT,
    float* __restrict__ wAlT, float* __restrict__ wScl,
    const float* __restrict__ o_w, ushort* __restrict__ owT) {
  __shared__ __attribute__((aligned(16))) char smem[77312];

  const int bid = blockIdx.x;
  const int tid = threadIdx.x;

  if (bid >= 512) {
    // ---- o_wT[h][d][v] bf16 path (24 blocks); uses 33.8 KB of smem
    const int b2 = bid - 512;
    const int h2 = b2 >> 2;
    const int db = (b2 & 3) * 64;
    ushort* t = (ushort*)smem;  // [64][264]
#pragma unroll
    for (int it = 0; it < 16; ++it) {
      const int v2 = it * 16 + (tid >> 4);
      const int dl = 4 * (tid & 15);
      const float4 x =
          *(const float4*)&o_w[((size_t)h2 * 256 + v2) * 256 + db + dl];
      t[(dl + 0) * 264 + v2] = (ushort)rnebf(x.x);
      t[(dl + 1) * 264 + v2] = (ushort)rnebf(x.y);
      t[(dl + 2) * 264 + v2] = (ushort)rnebf(x.z);
      t[(dl + 3) * 264 + v2] = (ushort)rnebf(x.w);
    }
    __syncthreads();
#pragma unroll
    for (int it = 0; it < 8; ++it) {
      const int idx = it * 256 + tid;
      const int d = idx >> 5;
      const int vv = (idx & 31) * 8;
      uint4 o;
      o.x = *(uint*)&t[d * 264 + vv + 0]; o.y = *(uint*)&t[d * 264 + vv + 2];
      o.z = *(uint*)&t[d * 264 + vv + 4]; o.w = *(uint*)&t[d * 264 + vv + 6];
      *(uint4*)&owT[((size_t)h2 * 256 + db + d) * 256 + vv] = o;
    }
    return;
  }

  const int bhx = bid & 15;
  if (bhx >= B_ * H_) return;
  const int nc = bid >> 4;
  const int bh = bhx;
  const int b = bh / H_, h = bh - b * H_;
  const int w = tid >> 6, l = tid & 63;
  const int lg = l >> 4, c16 = l & 15;
  const int cidx = bh * NC_ + nc;

  ushort* knB = (ushort*)smem;                   // 32K  (RAW k bf16)
  ushort* qnB = (ushort*)(smem + 32768);         // 32K  (RAW q bf16)
  ushort* Msc = (ushort*)(smem + 65536);         // [64][72] 9216 B
  float* bG = (float*)(smem + 74752);
  float* bB = bG + 64;
  float* bSc = bG + 128;
  float* bWl = bG + 192;
  float* bKg = bG + 256;
  float* bQg = bG + 320;
  float* bSk = bG + 384;
  float* bSq = bG + 448;
  float* bQe = bG + 512;

  const size_t srow0 = ((size_t)b * T_ + nc * C_) * H_ + h;
  if (tid < C_) {
    bG[tid] = Gc[cidx * C_ + tid];
    bB[tid] = beta[srow0 + (size_t)tid * H_];
  }
  __syncthreads();

  // ---- stage RAW q/k (bf16, XOR-swizzled rows of 512 B)
#pragma unroll
  for (int rr = 0; rr < 16; ++rr) {
    const int row = rr * 4 + w;
    const size_t g0 = (srow0 + (size_t)row * H_) * DK_;
    const float4 kv = *(const float4*)(k + g0 + 4 * l);
    const float4 qv = *(const float4*)(q + g0 + 4 * l);
    const int boff = row * 512 + ((8 * l) ^ ((row & 7) << 4));
    uint2 pk_, pq_;
    pk_.x = pkbf(kv.x, kv.y); pk_.y = pkbf(kv.z, kv.w);
    pq_.x = pkbf(qv.x, qv.y); pq_.y = pkbf(qv.z, qv.w);
    *(uint2*)((char*)knB + boff) = pk_;
    *(uint2*)((char*)qnB + boff) = pq_;
  }
  __syncthreads();

  // ---- MFMA: Mraw = q.k^T (32), Araw = k.k^T (32), Qdiag (8)
  f32x4 accm[4], acca[4];
  {
    const int xorv = (c16 & 7) << 4;
    const int rowA = 16 * w + c16;
    uint4 aq[8], ak[8];
#pragma unroll
    for (int kt = 0; kt < 8; ++kt) {
      const int coff = (64 * kt + 16 * lg) ^ xorv;
      aq[kt] = *(const uint4*)((char*)qnB + rowA * 512 + coff);
      ak[kt] = *(const uint4*)((char*)knB + rowA * 512 + coff);
    }
#pragma unroll
    for (int nt = 0; nt < 4; ++nt) {
      accm[nt] = (f32x4){0.f, 0.f, 0.f, 0.f};
      acca[nt] = (f32x4){0.f, 0.f, 0.f, 0.f};
    }
    f32x4 accq = (f32x4){0.f, 0.f, 0.f, 0.f};
#pragma unroll
    for (int nt = 0; nt < 4; ++nt) {
      const int rowB = 16 * nt + c16;
#pragma unroll
      for (int kt = 0; kt < 8; ++kt) {
        const uint4 bk =
            *(const uint4*)((char*)knB + rowB * 512 + ((64 * kt + 16 * lg) ^ xorv));
        const short8 bkf = u4_to_s8(bk);
        accm[nt] = __builtin_amdgcn_mfma_f32_16x16x32_bf16(u4_to_s8(aq[kt]),
                                                           bkf, accm[nt], 0, 0, 0);
        acca[nt] = __builtin_amdgcn_mfma_f32_16x16x32_bf16(u4_to_s8(ak[kt]),
                                                           bkf, acca[nt], 0, 0, 0);
      }
    }
#pragma unroll
    for (int kt = 0; kt < 8; ++kt) {
      const short8 bq = u4_to_s8(aq[kt]);
      accq = __builtin_amdgcn_mfma_f32_16x16x32_bf16(bq, bq, accq, 0, 0, 0);
    }
    // diag extraction: lanes with c16>>2 == lg hold t = 16w + c16 at r=c16&3
#pragma unroll
    for (int r = 0; r < 4; ++r) {
      if ((c16 >> 2) == lg && (c16 & 3) == r) {
        bKg[16 * w + c16] = acca[w][r];
        bQg[16 * w + c16] = accq[r];
      }
    }
  }
  __syncthreads();

  // ---- scalar pass: sq/sk + folded scales
  if (tid < C_) {
    const float gv = bG[tid];
    const float gend = bG[C_ - 1];
    const float skv = rsqrtf(bKg[tid] + 1e-6f);
    const float sqv = rsqrtf(bQg[tid] + 1e-6f) * 0.0625f;
    bSk[tid] = skv;
    bSq[tid] = sqv;
    bSc[tid] = __expf(gend - gv) * skv;
    bWl[tid] = bB[tid] * __expf(gv) * skv;
    bQe[tid] = sqv * __expf(gv);
  }
  __syncthreads();

  // ---- masks + scale + scatter: Msc (LDS), AlT -> GLOBAL fp32 [i][t]
  {
    float* gA = wAlT + (size_t)cidx * 4096;
#pragma unroll
    for (int nt = 0; nt < 4; ++nt) {
#pragma unroll
      for (int r = 0; r < 4; ++r) {
        const int t = 16 * w + 4 * lg + r;
        const int i = 16 * nt + c16;
        const float eg = __expf(bG[t] - bG[i]);
        const float ski = bSk[i];
        Msc[t * 72 + i] =
            (ushort)((i <= t) ? rnebf(accm[nt][r] * bSq[t] * ski * eg) : 0u);
        gA[i * 64 + t] =
            (i < t) ? bB[t] * bSk[t] * ski * eg * acca[nt][r] : 0.f;
      }
    }
  }
  // ---- column pass (thread = column d): kT emit + PRE-FS W store (bf16)
  {
    const int d = tid;
    ushort* wb = wWp + (size_t)cidx * C_ * 256;
#pragma unroll
    for (int e = 0; e < 8; ++e) {
      float vj[8];
#pragma unroll
      for (int j = 0; j < 8; ++j) {
        const int t = 8 * e + j;
        const float kv = bf2f(*(const ushort*)((char*)knB + t * 512 +
                                               ((2 * d) ^ ((t & 7) << 4))));
        vj[j] = kv;
        wb[t * 256 + d] = (ushort)rnebf(kv * bWl[t]);
      }
      uint4 o;
      o.x = pkbf(vj[0] * bSc[8 * e + 0], vj[1] * bSc[8 * e + 1]);
      o.y = pkbf(vj[2] * bSc[8 * e + 2], vj[3] * bSc[8 * e + 3]);
      o.z = pkbf(vj[4] * bSc[8 * e + 4], vj[5] * bSc[8 * e + 5]);
      o.w = pkbf(vj[6] * bSc[8 * e + 6], vj[7] * bSc[8 * e + 7]);
      *(uint4*)&wkT[((size_t)cidx * 256 + d) * C_ + 8 * e] = o;
    }
  }
  // ---- Qd emit: Qd = q_raw * sq * exp(G)
#pragma unroll
  for (int rr = 0; rr < 16; ++rr) {
    const int row = rr * 4 + w;
    const float qe = bQe[row];
    const uint2 pq =
        *(const uint2*)((char*)qnB + row * 512 + ((8 * l) ^ ((row & 7) << 4)));
    const float q0 = bf2f(pq.x), q1 = bf2f(pq.x >> 16);
    const float q2 = bf2f(pq.y), q3 = bf2f(pq.y >> 16);
    uint2 oq;
    oq.x = pkbf(q0 * qe, q1 * qe);
    oq.y = pkbf(q2 * qe, q3 * qe);
    *(uint2*)&wQd[(srow0 + (size_t)row * H_) * DK_ + 4 * l] = oq;
  }
  __syncthreads();  // Msc writes visible

  // ---- M store (vectorized from Msc)
  {
    const int row = tid >> 2;
#pragma unroll
    for (int e = 0; e < 2; ++e) {
      const int col = ((tid & 3) * 2 + e) * 8;
      *(uint4*)&wMp[(size_t)cidx * C_ * C_ + row * C_ + col] =
          *(const uint4*)&Msc[row * 72 + col];
    }
  }
  (void)wScl;
}

// ---------------------------------------------------------------------------
// Kernel 3b (parallel, register-heavy phase): forward substitution.
// (R20-proven) LDS 17.7 KB, single-pass dual FS in registers.
// ---------------------------------------------------------------------------
__global__ __launch_bounds__(256) void gdn_prep_fs_kernel(
    const float* __restrict__ v, const float* __restrict__ beta,
    const float* __restrict__ wAlT, ushort* __restrict__ wWp,
    uint2* __restrict__ wUp) {
  __shared__ __attribute__((aligned(16))) float AlT[64 * 68];
  __shared__ float bB[64];

  const int slot = blockIdx.x;
  const int bhx = slot & 15;
  if (bhx >= B_ * H_) return;
  const int nc = slot >> 4;
  const int bh = bhx;
  const int b = bh / H_, h = bh - b * H_;
  const int tid = threadIdx.x;
  const int cidx = bh * NC_ + nc;
  const size_t srow0 = ((size_t)b * T_ + nc * C_) * H_ + h;

  // stage AlT [64][64] global -> [64][68] LDS (coalesced)
  {
    const float* gA = wAlT + (size_t)cidx * 4096;
#pragma unroll
    for (int it = 0; it < 16; ++it) {
      const int idx = it * 256 + tid;
      AlT[(idx >> 6) * 68 + (idx & 63)] = gA[idx];
    }
  }
  if (tid < C_) bB[tid] = beta[srow0 + (size_t)tid * H_];
  __syncthreads();

  // ---- xw init: pre-FS W from wWp (coalesced bf16 column read)
  float xw[64];
  ushort* wb = wWp + (size_t)cidx * C_ * 256;
#pragma unroll
  for (int t = 0; t < C_; ++t) xw[t] = bf2f(wb[t * 256 + tid]);

  // ---- xu init: beta*V, coalesced column read
  float xu[64];
#pragma unroll
  for (int t = 0; t < C_; ++t)
    xu[t] = v[(srow0 + (size_t)t * H_) * DV_ + tid] * bB[t];

  // ---- forward substitution IN REGISTERS (AlT broadcast reads only)
#pragma unroll
  for (int tb = 0; tb < 8; ++tb) {
#pragma unroll
    for (int i = 0; i < 8 * tb; ++i) {
      const float xui = xu[i];
      const float xwi = xw[i];
      float av[8];
      *(float4*)&av[0] = *(float4*)&AlT[i * 68 + 8 * tb];
      *(float4*)&av[4] = *(float4*)&AlT[i * 68 + 8 * tb + 4];
#pragma unroll
      for (int e = 0; e < 8; ++e) {
        xu[8 * tb + e] = fmaf(-av[e], xui, xu[8 * tb + e]);
        xw[8 * tb + e] = fmaf(-av[e], xwi, xw[8 * tb + e]);
      }
    }
#pragma unroll
    for (int e = 1; e < 8; ++e)
#pragma unroll
      for (int m = 0; m < 7; ++m)
        if (m < e) {
          const float am = AlT[(8 * tb + m) * 68 + 8 * tb + e];
          xu[8 * tb + e] = fmaf(-am, xu[8 * tb + m], xu[8 * tb + e]);
          xw[8 * tb + e] = fmaf(-am, xw[8 * tb + m], xw[8 * tb + e]);
        }
  }
  // ---- store W (bf16 row-major, coalesced) and U (C/D-fragment pairs)
  {
#pragma unroll
    for (int row = 0; row < C_; ++row)
      wb[row * 256 + tid] = (ushort)rnebf(xw[row]);
    const int cbw = tid >> 4, c16s = tid & 15;
#pragma unroll
    for (int mt = 0; mt < 4; ++mt) {
#pragma unroll
      for (int lgi = 0; lgi < 4; ++lgi) {
        const int r0 = 16 * mt + 4 * lgi;
        uint2 val;
        val.x = pkbf(xu[r0 + 0], xu[r0 + 1]);
        val.y = pkbf(xu[r0 + 2], xu[r0 + 3]);
        wUp[(((size_t)cidx * 16 + cbw) * 4 + mt) * 64 + (lgi << 4) + c16s] = val;
      }
    }
  }
}

// ---------------------------------------------------------------------------
// Kernel 4 (sequential, MFMA, k-split): grid 256 = cb*16 + bh (XCD = bh%8);
// 2 waves per block: wave kh owns S rows kh*128..+127 for col-block cb.
// ---------------------------------------------------------------------------
__global__ __launch_bounds__(128, 1) void gdn_seq_kernel(
    const ushort* __restrict__ wkT, const ushort* __restrict__ wWp,
    const uint2* __restrict__ wUp, const float* __restrict__ lam,
    uint2* __restrict__ wDP, uint2* __restrict__ wSP) {
  const int bid = blockIdx.x;
  const int cb = bid >> 4, bhx = bid & 15;
  if (bhx >= B_ * H_) return;
  const int bh = bhx;
  const int tid = threadIdx.x;
  const int kh = tid >> 6, l = tid & 63;
  const int lg = l >> 4, c16 = l & 15;
  const int xorv = (c16 & 7) << 4;

  __shared__ ushort sW[2][16384];
  __shared__ ushort sK[2][16384];
  __shared__ uint2 sU[2][256];
  __shared__ f32x4 sX[2][4][64];
  __shared__ float sLam[NC_];

  auto stage = [&](int pp, int cidx2) {
    const char* gw_ = (const char*)(wWp + (size_t)cidx2 * 16384);
#pragma unroll
    for (int j = 0; j < 16; ++j) {
      const int i = kh * 16 + j;
      const int row = 2 * i + (l >> 5);
      const int colb = ((l & 31) * 16) ^ ((row & 7) << 4);
      gload_lds16(gw_ + row * 512 + colb, (char*)&sW[pp][0] + i * 1024);
    }
    const char* gk_ = (const char*)(wkT + (size_t)cidx2 * 16384);
#pragma unroll
    for (int j = 0; j < 16; ++j) {
      const int i = kh * 16 + j;
      const int row = 8 * i + (l >> 3);
      const int colb = ((l & 7) * 16) ^ ((row & 7) << 4);
      gload_lds16(gk_ + row * 128 + colb, (char*)&sK[pp][0] + i * 1024);
    }
    const char* gu_ = (const char*)wUp + ((size_t)cidx2 * 16 + cb) * 2048;
    gload_lds16(gu_ + kh * 1024 + l * 16, (char*)&sU[pp][0] + kh * 1024);
  };

  f32x4 S[8];
#pragma unroll
  for (int m2 = 0; m2 < 8; ++m2) S[m2] = (f32x4){0.f, 0.f, 0.f, 0.f};

  stage(0, bh * NC_ + 0);
  stage(1, bh * NC_ + 1);
  if (tid < NC_) sLam[tid] = lam[bh * NC_ + tid];
  asm volatile("s_waitcnt lgkmcnt(0)" ::: "memory");
  __builtin_amdgcn_sched_barrier(0);
  __builtin_amdgcn_s_barrier();
  __builtin_amdgcn_sched_barrier(0);

  for (int nc = 0; nc < NC_; ++nc) {
    const int pp = nc & 1;
    const int cidx = bh * NC_ + nc;
    if (nc == 0)
      asm volatile("s_waitcnt vmcnt(33)" ::: "memory");
    else if (nc == NC_ - 1)
      asm volatile("s_waitcnt vmcnt(5)" ::: "memory");
    else
      asm volatile("s_waitcnt vmcnt(38)" ::: "memory");
    __builtin_amdgcn_sched_barrier(0);
    __builtin_amdgcn_s_barrier();
    __builtin_amdgcn_sched_barrier(0);

    uint2 P[8];
#pragma unroll
    for (int m2 = 0; m2 < 8; ++m2) {
      P[m2].x = pkbf(S[m2][0], S[m2][1]);
      P[m2].y = pkbf(S[m2][2], S[m2][3]);
    }
    {
      uint4* sp4 = (uint4*)(wSP + (((size_t)cidx * 16 + cb) * 64 + l) * 16 +
                            kh * 8);
#pragma unroll
      for (int i = 0; i < 4; ++i) {
        uint4 o; o.x = P[2 * i].x; o.y = P[2 * i].y;
        o.z = P[2 * i + 1].x; o.w = P[2 * i + 1].y;
        sp4[i] = o;
      }
    }

    f32x4 pe[4], po[4];
#pragma unroll
    for (int mt = 0; mt < 4; ++mt) {
      pe[mt] = (f32x4){0.f, 0.f, 0.f, 0.f};
      po[mt] = (f32x4){0.f, 0.f, 0.f, 0.f};
    }
    const char* sWb = (const char*)&sW[pp][0];
#pragma unroll
    for (int ktl = 0; ktl < 4; ++ktl) {
      const int kt = kh * 4 + ktl;
      const short8 Bf = buildB(P[2 * ktl], P[2 * ktl + 1], lg, c16);
      const int colb = (64 * kt + 16 * lg) ^ xorv;
#pragma unroll
      for (int mt = 0; mt < 4; ++mt) {
        const uint4 aw = *(const uint4*)(sWb + (16 * mt + c16) * 512 + colb);
        if (ktl & 1)
          po[mt] = __builtin_amdgcn_mfma_f32_16x16x32_bf16(u4_to_s8(aw), Bf,
                                                           po[mt], 0, 0, 0);
        else
          pe[mt] = __builtin_amdgcn_mfma_f32_16x16x32_bf16(u4_to_s8(aw), Bf,
                                                           pe[mt], 0, 0, 0);
      }
    }
    f32x4 pl[4];
#pragma unroll
    for (int mt = 0; mt < 4; ++mt) {
      pl[mt] = pe[mt] + po[mt];
      sX[kh][mt][l] = pl[mt];
    }
    asm volatile("s_waitcnt lgkmcnt(0)" ::: "memory");
    __builtin_amdgcn_sched_barrier(0);
    __builtin_amdgcn_s_barrier();
    __builtin_amdgcn_sched_barrier(0);

    uint2 DP[4];
#pragma unroll
    for (int mt = 0; mt < 4; ++mt) {
      const f32x4 pr = sX[kh ^ 1][mt][l];
      const uint2 uu = sU[pp][mt * 64 + l];
      const float d0 = bf2f(uu.x) - (pl[mt][0] + pr[0]);
      const float d1 = bf2f(uu.x >> 16) - (pl[mt][1] + pr[1]);
      const float d2 = bf2f(uu.y) - (pl[mt][2] + pr[2]);
      const float d3 = bf2f(uu.y >> 16) - (pl[mt][3] + pr[3]);
      DP[mt].x = pkbf(d0, d1);
      DP[mt].y = pkbf(d2, d3);
    }
    {
      uint4* dp4 = (uint4*)(wDP + (((size_t)cidx * 16 + cb) * 64 + l) * 4);
      uint4 od;
      if (kh == 0) { od.x = DP[0].x; od.y = DP[0].y; od.z = DP[1].x; od.w = DP[1].y; }
      else         { od.x = DP[2].x; od.y = DP[2].y; od.z = DP[3].x; od.w = DP[3].y; }
      dp4[kh] = od;
    }
    const float lamC = sLam[nc];
#pragma unroll
    for (int m2 = 0; m2 < 8; ++m2) {
      S[m2][0] *= lamC; S[m2][1] *= lamC; S[m2][2] *= lamC; S[m2][3] *= lamC;
    }
    const char* sKb = (const char*)&sK[pp][0];
#pragma unroll
    for (int kt2 = 0; kt2 < 2; ++kt2) {
      const short8 Bd = buildB(DP[2 * kt2], DP[2 * kt2 + 1], lg, c16);
      const int colb = (64 * kt2 + 16 * lg) ^ xorv;
#pragma unroll
      for (int m2 = 0; m2 < 8; ++m2) {
        const int m2g = kh * 8 + m2;
        const uint4 ak = *(const uint4*)(sKb + (16 * m2g + c16) * 128 + colb);
        S[m2] = __builtin_amdgcn_mfma_f32_16x16x32_bf16(u4_to_s8(ak), Bd,
                                                        S[m2], 0, 0, 0);
      }
    }
    __builtin_amdgcn_sched_barrier(0);
    __builtin_amdgcn_s_barrier();
    __builtin_amdgcn_sched_barrier(0);
    if (nc + 2 < NC_) stage(pp, cidx + 2);
    __builtin_amdgcn_sched_barrier(0);
  }
}

// ---------------------------------------------------------------------------
// Kernel 5 (parallel, MFMA, fused epilogue): grid 512 = nc*16 + bh.
// ---------------------------------------------------------------------------
__global__ __launch_bounds__(256) void gdn_ofin_kernel(
    const ushort* __restrict__ wQd, const ushort* __restrict__ wMp,
    const uint2* __restrict__ wDP, const uint2* __restrict__ wSP,
    const float* __restrict__ sgate, const float* __restrict__ norm_w,
    const ushort* __restrict__ owT, float* __restrict__ out) {
  const int slot = blockIdx.x;
  const int bhx = slot & 15;
  if (bhx >= B_ * H_) return;
  const int nc = slot >> 4;
  const int bh = bhx;
  const int cidx = bh * NC_ + nc;
  const int b = bh / H_, h = bh - b * H_;
  const int tid = threadIdx.x;
  const int w = tid >> 6, l = tid & 63;
  const int lg = l >> 4, c16 = l & 15;
  const size_t t0 = (size_t)b * T_ + nc * C_;

  __shared__ ushort onl[64 * 256];
  __shared__ float red[64][4];
  __shared__ float rowf[64];

  f32x4 acc[4][4];
#pragma unroll
  for (int mt = 0; mt < 4; ++mt)
#pragma unroll
    for (int nt = 0; nt < 4; ++nt) acc[mt][nt] = (f32x4){0.f, 0.f, 0.f, 0.f};

#pragma unroll
  for (int nt = 0; nt < 4; ++nt) {
    const int cbwq = 4 * w + nt;
    uint2 SPl[16];
    const uint4* sp4 =
        (const uint4*)(wSP + (((size_t)cidx * 16 + cbwq) * 64 + l) * 16);
#pragma unroll
    for (int i = 0; i < 8; ++i) {
      const uint4 t4 = sp4[i];
      SPl[2 * i].x = t4.x; SPl[2 * i].y = t4.y;
      SPl[2 * i + 1].x = t4.z; SPl[2 * i + 1].y = t4.w;
    }
#pragma unroll
    for (int kt = 0; kt < 8; ++kt) {
      const short8 Bf = buildB(SPl[2 * kt], SPl[2 * kt + 1], lg, c16);
#pragma unroll
      for (int mt = 0; mt < 4; ++mt) {
        const uint4 aq = *(const uint4*)&wQd[((t0 + 16 * mt + c16) * H_ + h) *
                                                 (size_t)DK_ +
                                             32 * kt + 8 * lg];
        acc[mt][nt] = __builtin_amdgcn_mfma_f32_16x16x32_bf16(
            u4_to_s8(aq), Bf, acc[mt][nt], 0, 0, 0);
      }
    }
  }
  const ushort* Mb = wMp + (size_t)cidx * C_ * C_;
#pragma unroll
  for (int nt = 0; nt < 4; ++nt) {
    const int cbwq = 4 * w + nt;
    uint2 DPl[4];
    {
      const uint4* dp4 =
          (const uint4*)(wDP + (((size_t)cidx * 16 + cbwq) * 64 + l) * 4);
      const uint4 a0 = dp4[0], a1 = dp4[1];
      DPl[0].x = a0.x; DPl[0].y = a0.y; DPl[1].x = a0.z; DPl[1].y = a0.w;
      DPl[2].x = a1.x; DPl[2].y = a1.y; DPl[3].x = a1.z; DPl[3].y = a1.w;
    }
#pragma unroll
    for (int kt2 = 0; kt2 < 2; ++kt2) {
      const short8 Bf = buildB(DPl[2 * kt2], DPl[2 * kt2 + 1], lg, c16);
#pragma unroll
      for (int mt = 0; mt < 4; ++mt) {
        const uint4 am =
            *(const uint4*)&Mb[(16 * mt + c16) * C_ + 32 * kt2 + 8 * lg];
        acc[mt][nt] = __builtin_amdgcn_mfma_f32_16x16x32_bf16(
            u4_to_s8(am), Bf, acc[mt][nt], 0, 0, 0);
      }
    }
  }

  float ss[4][4];
#pragma unroll
  for (int mt = 0; mt < 4; ++mt)
#pragma unroll
    for (int r = 0; r < 4; ++r) {
      float s = acc[mt][0][r] * acc[mt][0][r];
      s = fmaf(acc[mt][1][r], acc[mt][1][r], s);
      s = fmaf(acc[mt][2][r], acc[mt][2][r], s);
      s = fmaf(acc[mt][3][r], acc[mt][3][r], s);
      s += __shfl_xor(s, 1);
      s += __shfl_xor(s, 2);
      s += __shfl_xor(s, 4);
      s += __shfl_xor(s, 8);
      ss[mt][r] = s;
    }
  if (c16 == 0) {
#pragma unroll
    for (int mt = 0; mt < 4; ++mt)
#pragma unroll
      for (int r = 0; r < 4; ++r) red[16 * mt + 4 * lg + r][w] = ss[mt][r];
  }
  __syncthreads();
  if (tid < 64) {
    const float ms =
        (red[tid][0] + red[tid][1] + red[tid][2] + red[tid][3]) * (1.f / DV_);
    const float sg = sgate[(t0 + tid) * H_ + h];
    rowf[tid] = rsqrtf(ms + 1e-5f) * sg;
  }
  __syncthreads();

  {
    char* onb = (char*)onl;
#pragma unroll
    for (int mt = 0; mt < 4; ++mt) {
      float rf[4];
#pragma unroll
      for (int r = 0; r < 4; ++r) rf[r] = rowf[16 * mt + 4 * lg + r];
#pragma unroll
      for (int nt = 0; nt < 4; ++nt) {
        const int c = (4 * w + nt) * 16 + c16;
        const float nwv = norm_w[c];
#pragma unroll
        for (int r = 0; r < 4; ++r) {
          const int row = 16 * mt + 4 * lg + r;
          const float v = acc[mt][nt][r] * rf[r] * nwv;
          *(ushort*)(onb + row * 512 + ((2 * c) ^ ((row & 7) << 4))) =
              (ushort)rnebf(v);
        }
      }
    }
  }
  __syncthreads();

  f32x4 acc2[4][4];
#pragma unroll
  for (int mt = 0; mt < 4; ++mt)
#pragma unroll
    for (int nt2 = 0; nt2 < 4; ++nt2)
      acc2[mt][nt2] = (f32x4){0.f, 0.f, 0.f, 0.f};
  {
    const char* onb = (const char*)onl;
#pragma unroll
    for (int kt = 0; kt < 8; ++kt) {
      uint4 af[4];
#pragma unroll
      for (int mt = 0; mt < 4; ++mt)
        af[mt] = *(const uint4*)(onb + (16 * mt + c16) * 512 +
                                 ((64 * kt + 16 * lg) ^ ((c16 & 7) << 4)));
#pragma unroll
      for (int nt2 = 0; nt2 < 4; ++nt2) {
        const uint4 bf = *(const uint4*)&owT[((size_t)h * 256 +
                                              (4 * w + nt2) * 16 + c16) *
                                                 256 +
                                             32 * kt + 8 * lg];
#pragma unroll
        for (int mt = 0; mt < 4; ++mt)
          acc2[mt][nt2] = __builtin_amdgcn_mfma_f32_16x16x32_bf16(
              u4_to_s8(af[mt]), u4_to_s8(bf), acc2[mt][nt2], 0, 0, 0);
      }
    }
  }
#pragma unroll
  for (int mt = 0; mt < 4; ++mt)
#pragma unroll
    for (int nt2 = 0; nt2 < 4; ++nt2)
#pragma unroll
      for (int r = 0; r < 4; ++r)
        out[((t0 + 16 * mt + 4 * lg + r) * H_ + h) * (size_t)DK_ +
            (4 * w + nt2) * 16 + c16] = acc2[mt][nt2][r];
}

// ---------------------------------------------------------------------------
extern "C" void kernel_launch(void* const* d_in, const int* in_sizes, int n_in,
                              void* d_out, int out_size, void* d_ws,
                              size_t ws_size, hipStream_t stream) {
  const float* hab = (const float*)d_in[0];
  const float* hg = (const float*)d_in[1];
  const float* q = (const float*)d_in[2];
  const float* k = (const float*)d_in[3];
  const float* v = (const float*)d_in[4];
  const float* b_w = (const float*)d_in[5];
  const float* a_w = (const float*)d_in[6];
  const float* A_log = (const float*)d_in[7];
  const float* dt_bias = (const float*)d_in[8];
  const float* g_w = (const float*)d_in[9];
  const float* norm_w = (const float*)d_in[10];
  const float* o_w = (const float*)d_in[11];
  float* out = (float*)d_out;

  float* ws = (float*)d_ws;
  const size_t NBT = (size_t)B_ * T_ * H_;  // 24576
  float* w_beta = ws;
  float* w_g = ws + NBT;
  float* w_sg = ws + 2 * NBT;
  float* w_G = ws + 5 * NBT;
  float* w_lam = ws + 7 * NBT;                     // B*H*NC = 384 (pad 1024)
  ushort* w_Qd = (ushort*)(ws + 7 * NBT + 1024);   // 12,582,912 u16
  ushort* w_kT = w_Qd + (size_t)12582912;          // 6,291,456 u16
  ushort* w_W = w_kT + (size_t)6291456;            // 6,291,456 u16
  ushort* w_M = w_W + (size_t)6291456;             // 1,572,864 u16
  uint2* w_U = (uint2*)(w_M + (size_t)1572864);    // 1,572,864 uint2
  uint2* w_DP = w_U + (size_t)1572864;             // 1,572,864 uint2
  uint2* w_SP = w_DP + (size_t)1572864;            // 6,291,456 uint2
  ushort* w_owT = (ushort*)(w_SP + (size_t)6291456);  // 393,216 u16
  float* w_AlT = (float*)(w_owT + (size_t)393216);    // 1,572,864 f32

  hipLaunchKernelGGL(gdn_proj_kernel, dim3(512), dim3(256), 0, stream,
                     hab, hg, b_w, a_w, g_w, A_log, dt_bias, w_beta, w_g,
                     w_sg);
  hipLaunchKernelGGL(gdn_cum_kernel, dim3(B_ * H_), dim3(256), 0, stream,
                     w_g, w_G, w_lam);
  hipLaunchKernelGGL(gdn_prep_mfma_kernel, dim3(512 + 24), dim3(256), 0,
                     stream, q, k, w_beta, w_G, w_W, w_M, w_Qd, w_kT, w_AlT,
                     nullptr, o_w, w_owT);
  hipLaunchKernelGGL(gdn_prep_fs_kernel, dim3(512), dim3(256), 0, stream,
                     v, w_beta, w_AlT, w_W, w_U);
  hipLaunchKernelGGL(gdn_seq_kernel, dim3(256), dim3(128), 0, stream,
                     w_kT, w_W, w_U, w_lam, w_DP, w_SP);
  hipLaunchKernelGGL(gdn_ofin_kernel, dim3(512), dim3(256), 0, stream,
                     w_Qd, w_M, w_DP, w_SP, w_sg, norm_w, w_owT, out);
}